// Round 6
// baseline (562.874 us; speedup 1.0000x reference)
//
#include <hip/hip_runtime.h>
#include <hip/hip_fp16.h>

typedef float   f32x4   __attribute__((ext_vector_type(4)));
typedef float   f32x2   __attribute__((ext_vector_type(2)));
typedef short   short8v __attribute__((ext_vector_type(8)));
typedef unsigned short ushort8v __attribute__((ext_vector_type(8)));
typedef int     int2v   __attribute__((ext_vector_type(2)));
typedef unsigned int   u32;
typedef unsigned short u16;

#define DEVI static __device__ __forceinline__

DEVI u16 f2bf(float f) {
    u32 u = __builtin_bit_cast(u32, f);
    u += 0x7FFFu + ((u >> 16) & 1u);   // RNE (inputs finite)
    return (u16)(u >> 16);
}
DEVI float bf2f(u16 h) { return __builtin_bit_cast(float, (u32)h << 16); }

// async global->LDS, 16B per lane; lds ptr must be wave-uniform (lane*16 added by HW)
DEVI void gl_lds16(const u16* g, u16* l) {
    __builtin_amdgcn_global_load_lds(
        (const __attribute__((address_space(1))) u32*)(const void*)g,
        (__attribute__((address_space(3))) u32*)(void*)l, 16, 0, 0);
}

// ---------------------------------------------------------------------------
// convert f32 -> bf16 (optionally scaled). n8 = elements/8.
// ---------------------------------------------------------------------------
__global__ __launch_bounds__(256) void convert_kernel(
    const float* __restrict__ src, u16* __restrict__ dst, float scale, int n8) {
    int idx = blockIdx.x * 256 + threadIdx.x;
    if (idx >= n8) return;
    const float* p = src + (size_t)idx * 8;
    f32x4 a = *(const f32x4*)p, b = *(const f32x4*)(p + 4);
    ushort8v o;
    o[0]=f2bf(a[0]*scale); o[1]=f2bf(a[1]*scale); o[2]=f2bf(a[2]*scale); o[3]=f2bf(a[3]*scale);
    o[4]=f2bf(b[0]*scale); o[5]=f2bf(b[1]*scale); o[6]=f2bf(b[2]*scale); o[7]=f2bf(b[3]*scale);
    *(ushort8v*)(dst + (size_t)idx * 8) = o;
}

// ---------------------------------------------------------------------------
// prep_cache: dequant cache -> bf16 K rows (kcb rows 0..4095) + bf16 V^T cols
// 0..4095 + exact requant of window rows 512..4095. Grid 4096, 256 thr.
// ---------------------------------------------------------------------------
__global__ __launch_bounds__(256) void prep_cache_kernel(
    const int* __restrict__ kq, const int* __restrict__ vq,
    const float* __restrict__ ks, const float* __restrict__ vs,
    u16* __restrict__ kcb, u16* __restrict__ vt,
    float* __restrict__ oktq, float* __restrict__ ovtq,
    float* __restrict__ oksc, float* __restrict__ ovsc) {
    __shared__ u16 Vs[64][132];
    __shared__ float skL[64], svL[64];
    const int tid = threadIdx.x;
    const int bh = blockIdx.x >> 6, kt = blockIdx.x & 63;
    const int key0 = kt << 6;
    const size_t rowbase = (size_t)bh * 4096 + key0;
    if (tid < 64) { skL[tid] = ks[rowbase + tid]; svL[tid] = vs[rowbase + tid]; }
    __syncthreads();
    const int lane = tid & 63, w = tid >> 6;
    u32* kcw = (u32*)kcb;
    #pragma unroll 4
    for (int s = 0; s < 16; ++s) {
        const int key = s * 4 + w;
        const size_t row = rowbase + key;
        const float sk = skL[key], sv = svL[key];
        int2v kv = *(const int2v*)(kq + row * 128 + lane * 2);
        int2v vv = *(const int2v*)(vq + row * 128 + lane * 2);
        float kx0 = (float)kv[0] * sk, kx1 = (float)kv[1] * sk;
        float vx0 = (float)vv[0] * sv, vx1 = (float)vv[1] * sv;
        kcw[(size_t)(bh * 4608 + key0 + key) * 64 + lane] =
            (u32)f2bf(kx0) | ((u32)f2bf(kx1) << 16);
        *(u32*)&Vs[key][lane * 2] = (u32)f2bf(vx0) | ((u32)f2bf(vx1) << 16);
        float kam = fmaxf(fabsf(kx0), fabsf(kx1));
        float vam = fmaxf(fabsf(vx0), fabsf(vx1));
        #pragma unroll
        for (int off = 1; off < 64; off <<= 1) {
            kam = fmaxf(kam, __shfl_xor(kam, off, 64));
            vam = fmaxf(vam, __shfl_xor(vam, off, 64));
        }
        const int r = key0 + key;
        if (r >= 512) {
            const size_t orow = (size_t)bh * 4096 + (size_t)(r - 512);
            float kscale = fmaxf(kam / 127.0f, 1e-8f);
            float vscale = fmaxf(vam / 127.0f, 1e-8f);
            float kinv = 1.0f / kscale, vinv = 1.0f / vscale;
            f32x2 ko, vo;
            ko[0] = fminf(fmaxf(rintf(kx0 * kinv), -127.f), 127.f);
            ko[1] = fminf(fmaxf(rintf(kx1 * kinv), -127.f), 127.f);
            vo[0] = fminf(fmaxf(rintf(vx0 * vinv), -127.f), 127.f);
            vo[1] = fminf(fmaxf(rintf(vx1 * vinv), -127.f), 127.f);
            *(f32x2*)(oktq + orow * 128 + lane * 2) = ko;
            *(f32x2*)(ovtq + orow * 128 + lane * 2) = vo;
            if (lane == 0) {
                oksc[orow] = __half2float(__float2half(kscale));
                ovsc[orow] = __half2float(__float2half(vscale));
            }
        }
    }
    __syncthreads();
    const int d = tid >> 1, half = tid & 1;
    u16* obase = vt + ((size_t)bh * 128 + d) * 4608 + key0 + half * 32;
    #pragma unroll
    for (int c = 0; c < 4; ++c) {
        ushort8v tv;
        #pragma unroll
        for (int e = 0; e < 8; ++e) tv[e] = Vs[half * 32 + c * 8 + e][d];
        *(ushort8v*)(obase + c * 8) = tv;
    }
}

// ---------------------------------------------------------------------------
// bf16 GEMM  C[m][n] = sum_k A[m][k] * B[n][k]  (2048^3).
// BM=128 BN=64 BK=64, 128 threads = 2 waves (each 64x64 out, acc[4][4]).
// 48KB LDS -> 3 blocks/CU. gload_lds + XOR swizzle + 2-phase dbuf.
// MODE 0: q bf16 head-split; 1: kcb rows 4096..; 2: vnb head-split; 3: f32.
// ---------------------------------------------------------------------------
template <int MODE>
__global__ __launch_bounds__(128) void gemm_bf16_kernel(
    const u16* __restrict__ A, const u16* __restrict__ Bw,
    void* __restrict__ Cout) {
    __shared__ u16 As[2][128 * 64];
    __shared__ u16 Bs[2][64 * 64];
    const int tid = threadIdx.x, lane = tid & 63, w = tid >> 6;
    const int sid = (blockIdx.x & 7) * 64 + (blockIdx.x >> 3);  // XCD-chunked
    const int bm = sid & 15, bn = sid >> 4;
    const int m0 = bm * 128, n0 = bn * 64;
    const int wm = w * 64;
    const int r16 = lane & 15, kb = lane >> 4;

    f32x4 acc[4][4] = {};

    auto stage = [&](int bi, int k0) {
        #pragma unroll
        for (int i = 0; i < 8; ++i) {
            int s = i * 128 + tid;
            int row = s >> 3, l = (s & 7) ^ (row & 7);
            gl_lds16(A + (size_t)(m0 + row) * 2048 + k0 + l * 8,
                     &As[bi][(i * 128 + (tid & ~63)) * 8]);
        }
        #pragma unroll
        for (int i = 0; i < 4; ++i) {
            int s = i * 128 + tid;
            int row = s >> 3, l = (s & 7) ^ (row & 7);
            gl_lds16(Bw + (size_t)(n0 + row) * 2048 + k0 + l * 8,
                     &Bs[bi][(i * 128 + (tid & ~63)) * 8]);
        }
    };

    stage(0, 0);
    __syncthreads();
    int cur = 0;
    for (int t = 0; t < 32; ++t) {
        if (t < 31) stage(cur ^ 1, (t + 1) * 64);
        short8v af[4][2], bf[4][2];
        #pragma unroll
        for (int mf = 0; mf < 4; ++mf) {
            int row = wm + mf * 16 + r16;
            #pragma unroll
            for (int ksv = 0; ksv < 2; ++ksv) {
                int blk = (ksv * 4 + kb) ^ (row & 7);
                af[mf][ksv] = __builtin_bit_cast(short8v,
                    *(const ushort8v*)&As[cur][row * 64 + blk * 8]);
            }
        }
        #pragma unroll
        for (int nf = 0; nf < 4; ++nf) {
            int row = nf * 16 + r16;
            #pragma unroll
            for (int ksv = 0; ksv < 2; ++ksv) {
                int blk = (ksv * 4 + kb) ^ (row & 7);
                bf[nf][ksv] = __builtin_bit_cast(short8v,
                    *(const ushort8v*)&Bs[cur][row * 64 + blk * 8]);
            }
        }
        #pragma unroll
        for (int mf = 0; mf < 4; ++mf)
            #pragma unroll
            for (int nf = 0; nf < 4; ++nf)
                #pragma unroll
                for (int ksv = 0; ksv < 2; ++ksv)
                    acc[mf][nf] = __builtin_amdgcn_mfma_f32_16x16x32_bf16(
                        af[mf][ksv], bf[nf][ksv], acc[mf][nf], 0, 0, 0);
        __syncthreads();
        cur ^= 1;
    }

    #pragma unroll
    for (int mf = 0; mf < 4; ++mf)
        #pragma unroll
        for (int nf = 0; nf < 4; ++nf)
            #pragma unroll
            for (int v = 0; v < 4; ++v) {
                int mg = m0 + wm + mf * 16 + kb * 4 + v;
                int ng = n0 + nf * 16 + r16;
                float val = acc[mf][nf][v];
                if (MODE == 0 || MODE == 2) {
                    ((u16*)Cout)[(((size_t)(mg >> 9) * 16 + (ng >> 7)) * 512 +
                                  (mg & 511)) * 128 + (ng & 127)] = f2bf(val);
                } else if (MODE == 1) {
                    size_t bh = (size_t)(mg >> 9) * 16 + (ng >> 7);
                    ((u16*)Cout)[(bh * 4608 + 4096 + (mg & 511)) * 128 + (ng & 127)] = f2bf(val);
                } else {
                    ((float*)Cout)[(size_t)mg * 2048 + ng] = val;
                }
            }
}

// ---------------------------------------------------------------------------
// quant_new: quantize new K/V rows + V^T cols 4096..4607. Grid 512, 256 thr.
// ---------------------------------------------------------------------------
__global__ __launch_bounds__(256) void quant_new_kernel(
    const u16* __restrict__ kcb, const u16* __restrict__ vnb,
    u16* __restrict__ vt,
    float* __restrict__ oktq, float* __restrict__ ovtq,
    float* __restrict__ oksc, float* __restrict__ ovsc) {
    __shared__ u16 Vs[64][132];
    const int tid = threadIdx.x;
    const int bh = blockIdx.x >> 3, kt = blockIdx.x & 7;
    const int i0 = kt << 6;
    const int lane = tid & 63, w = tid >> 6;
    #pragma unroll 4
    for (int s = 0; s < 16; ++s) {
        const int key = s * 4 + w;
        const int i = i0 + key;
        u32 ku = *(const u32*)(kcb + ((size_t)bh * 4608 + 4096 + i) * 128 + lane * 2);
        u32 vu = *(const u32*)(vnb + ((size_t)bh * 512 + i) * 128 + lane * 2);
        float kx0 = bf2f((u16)ku), kx1 = bf2f((u16)(ku >> 16));
        float vx0 = bf2f((u16)vu), vx1 = bf2f((u16)(vu >> 16));
        *(u32*)&Vs[key][lane * 2] = vu;
        float kam = fmaxf(fabsf(kx0), fabsf(kx1));
        float vam = fmaxf(fabsf(vx0), fabsf(vx1));
        #pragma unroll
        for (int off = 1; off < 64; off <<= 1) {
            kam = fmaxf(kam, __shfl_xor(kam, off, 64));
            vam = fmaxf(vam, __shfl_xor(vam, off, 64));
        }
        float kscale = fmaxf(kam / 127.0f, 1e-8f);
        float vscale = fmaxf(vam / 127.0f, 1e-8f);
        float kinv = 1.0f / kscale, vinv = 1.0f / vscale;
        const size_t orow = (size_t)bh * 4096 + 3584 + i;
        f32x2 ko, vo;
        ko[0] = fminf(fmaxf(rintf(kx0 * kinv), -127.f), 127.f);
        ko[1] = fminf(fmaxf(rintf(kx1 * kinv), -127.f), 127.f);
        vo[0] = fminf(fmaxf(rintf(vx0 * vinv), -127.f), 127.f);
        vo[1] = fminf(fmaxf(rintf(vx1 * vinv), -127.f), 127.f);
        *(f32x2*)(oktq + orow * 128 + lane * 2) = ko;
        *(f32x2*)(ovtq + orow * 128 + lane * 2) = vo;
        if (lane == 0) {
            oksc[orow] = __half2float(__float2half(kscale));
            ovsc[orow] = __half2float(__float2half(vscale));
        }
    }
    __syncthreads();
    const int d = tid >> 1, half = tid & 1;
    u16* obase = vt + ((size_t)bh * 128 + d) * 4608 + 4096 + i0 + half * 32;
    #pragma unroll
    for (int c = 0; c < 4; ++c) {
        ushort8v tv;
        #pragma unroll
        for (int e = 0; e < 8; ++e) tv[e] = Vs[half * 32 + c * 8 + e][d];
        *(ushort8v*)(obase + c * 8) = tv;
    }
}

// ---------------------------------------------------------------------------
// attn: 256 blocks = (b,h) x 4 q-tiles of 128 rows; 4 waves x 32 q-rows.
// Each K/V fragment read feeds 2 MFMAs (qg=0,1) -> 2x MFMA per LDS byte.
// Swapped QK^T, in-register softmax, defer-max, cvt_pk P-pack.
// ---------------------------------------------------------------------------
__global__ __launch_bounds__(256, 1) void attn_kernel(
    const u16* __restrict__ qb, const u16* __restrict__ kcb,
    const u16* __restrict__ vt, u16* __restrict__ yb) {
    __shared__ u16 Ks[2][64 * 128];
    __shared__ u16 Vl[2][128 * 64];
    __shared__ u32 Pl[4][32][36];   // [wave][q-row][k-word], +4 pad words

    const int tid = threadIdx.x, lane = tid & 63, w = tid >> 6;
    const int p = blockIdx.x;
    const int xcd = p & 7, i = p >> 3;
    const int bh = (i & 7) * 8 + xcd;     // bh%8 == xcd -> all 4 qt on one XCD
    const int qt = i >> 3;
    const int b = bh >> 4, h = bh & 15;
    const int r16 = lane & 15, kb = lane >> 4;

    const u16* qp0 = qb + ((size_t)bh * 512 + qt * 128 + w * 32 + r16) * 128;
    short8v qf0[4], qf1[4];
    #pragma unroll
    for (int f = 0; f < 4; ++f) {
        qf0[f] = __builtin_bit_cast(short8v, *(const ushort8v*)(qp0 + f * 32 + kb * 8));
        qf1[f] = __builtin_bit_cast(short8v, *(const ushort8v*)(qp0 + 16 * 128 + f * 32 + kb * 8));
    }

    f32x4 Of0[8] = {}, Of1[8] = {};
    float m0_ = -3.0e38f, l0_ = 0.f, m1_ = -3.0e38f, l1_ = 0.f;

    const size_t kbase = (size_t)bh * 4608 * 128;
    const size_t vbase = (size_t)bh * 128 * 4608;
    const int nt = 66 + qt * 2;

    auto STAGE = [&](int bi, int kt) {
        #pragma unroll
        for (int ii = 0; ii < 4; ++ii) {
            int s = ii * 256 + tid;
            int row = s >> 4, l = (s & 15) ^ (row & 7);
            gl_lds16(kcb + kbase + (size_t)(kt * 64 + row) * 128 + l * 8,
                     &Ks[bi][(ii * 256 + (tid & ~63)) * 8]);
        }
        #pragma unroll
        for (int ii = 0; ii < 4; ++ii) {
            int s = ii * 256 + tid;
            int row = s >> 3, l = (s & 7) ^ (row & 7);
            gl_lds16(vt + vbase + (size_t)row * 4608 + kt * 64 + l * 8,
                     &Vl[bi][(ii * 256 + (tid & ~63)) * 8]);
        }
    };

    STAGE(0, 0);
    __syncthreads();
    int cur = 0;
    for (int kt = 0; kt < nt; ++kt) {
        if (kt + 1 < nt) STAGE(cur ^ 1, kt + 1);

        // S^T tiles for both q-groups: Sf[nf][v] = S[q=r16][k=nf*16+kb*4+v]
        f32x4 S0[4] = {}, S1[4] = {};
        __builtin_amdgcn_s_setprio(1);
        #pragma unroll
        for (int nf = 0; nf < 4; ++nf) {
            int krow = nf * 16 + r16;
            #pragma unroll
            for (int ksv = 0; ksv < 4; ++ksv) {
                int blk = (ksv * 4 + kb) ^ (krow & 7);
                short8v kf = __builtin_bit_cast(short8v,
                    *(const ushort8v*)&Ks[cur][krow * 128 + blk * 8]);
                S0[nf] = __builtin_amdgcn_mfma_f32_16x16x32_bf16(kf, qf0[ksv], S0[nf], 0, 0, 0);
                S1[nf] = __builtin_amdgcn_mfma_f32_16x16x32_bf16(kf, qf1[ksv], S1[nf], 0, 0, 0);
            }
        }
        __builtin_amdgcn_s_setprio(0);

        auto softmax_pack = [&](f32x4* Sf, f32x4* Of, float& m_i, float& l_i, int qg) {
            if (kt >= 64) {  // causal mask within the new segment
                const int kn0 = (kt - 64) * 64 + kb * 4;
                const int qn = qt * 128 + w * 32 + qg * 16 + r16;
                #pragma unroll
                for (int nf = 0; nf < 4; ++nf)
                    #pragma unroll
                    for (int v = 0; v < 4; ++v)
                        if (kn0 + nf * 16 + v > qn) Sf[nf][v] = -3.0e38f;
            }
            float mx;
            {
                f32x4 t4 = __builtin_elementwise_max(Sf[0], Sf[1]);
                f32x4 u4 = __builtin_elementwise_max(Sf[2], Sf[3]);
                t4 = __builtin_elementwise_max(t4, u4);
                mx = fmaxf(fmaxf(t4[0], t4[1]), fmaxf(t4[2], t4[3]));
                mx = fmaxf(mx, __shfl_xor(mx, 16, 64));
                mx = fmaxf(mx, __shfl_xor(mx, 32, 64));
            }
            if (__ballot(mx > m_i + 8.f)) {
                float mnew = fmaxf(m_i, mx);
                float alpha = __expf(m_i - mnew);
                m_i = mnew;
                l_i *= alpha;
                #pragma unroll
                for (int v = 0; v < 4; ++v) {
                    float av = __shfl(alpha, kb * 4 + v, 64);
                    #pragma unroll
                    for (int of = 0; of < 8; ++of) Of[of][v] *= av;
                }
            }
            #pragma unroll
            for (int nf = 0; nf < 4; ++nf) {
                float s0 = __expf(Sf[nf][0] - m_i);
                float s1 = __expf(Sf[nf][1] - m_i);
                float s2 = __expf(Sf[nf][2] - m_i);
                float s3 = __expf(Sf[nf][3] - m_i);
                Sf[nf][0] = s0; Sf[nf][1] = s1; Sf[nf][2] = s2; Sf[nf][3] = s3;
                l_i += (s0 + s1) + (s2 + s3);
            }
            #pragma unroll
            for (int nf = 0; nf < 4; ++nf) {
                u32 p0, p1;
                asm("v_cvt_pk_bf16_f32 %0, %1, %2" : "=v"(p0) : "v"(Sf[nf][0]), "v"(Sf[nf][1]));
                asm("v_cvt_pk_bf16_f32 %0, %1, %2" : "=v"(p1) : "v"(Sf[nf][2]), "v"(Sf[nf][3]));
                Pl[w][qg * 16 + r16][nf * 8 + kb * 2 + 0] = p0;
                Pl[w][qg * 16 + r16][nf * 8 + kb * 2 + 1] = p1;
            }
        };
        softmax_pack(S0, Of0, m0_, l0_, 0);
        softmax_pack(S1, Of1, m1_, l1_, 1);
        asm volatile("s_waitcnt lgkmcnt(0)" ::: "memory");

        // O += P V   (each V fragment feeds both q-groups)
        __builtin_amdgcn_s_setprio(1);
        #pragma unroll
        for (int ka = 0; ka < 2; ++ka) {
            short8v pf0 = __builtin_bit_cast(short8v,
                *(const ushort8v*)&Pl[w][r16][ka * 16 + kb * 4]);
            short8v pf1 = __builtin_bit_cast(short8v,
                *(const ushort8v*)&Pl[w][16 + r16][ka * 16 + kb * 4]);
            #pragma unroll
            for (int of = 0; of < 8; ++of) {
                int vrow = of * 16 + r16;
                int blk = (ka * 4 + kb) ^ (vrow & 7);
                short8v vf = __builtin_bit_cast(short8v,
                    *(const ushort8v*)&Vl[cur][vrow * 64 + blk * 8]);
                Of0[of] = __builtin_amdgcn_mfma_f32_16x16x32_bf16(pf0, vf, Of0[of], 0, 0, 0);
                Of1[of] = __builtin_amdgcn_mfma_f32_16x16x32_bf16(pf1, vf, Of1[of], 0, 0, 0);
            }
        }
        __builtin_amdgcn_s_setprio(0);

        __syncthreads();
        cur ^= 1;
    }

    auto epilogue = [&](f32x4* Of, float l_i, int qg) {
        float lt = l_i;
        lt += __shfl_xor(lt, 16, 64);
        lt += __shfl_xor(lt, 32, 64);
        float linv = 1.0f / lt;
        float invl[4];
        #pragma unroll
        for (int v = 0; v < 4; ++v) invl[v] = __shfl(linv, kb * 4 + v, 64);
        #pragma unroll
        for (int of = 0; of < 8; ++of)
            #pragma unroll
            for (int v = 0; v < 4; ++v) {
                int qrow = qt * 128 + w * 32 + qg * 16 + kb * 4 + v;
                int d = of * 16 + r16;
                yb[(size_t)(b * 512 + qrow) * 2048 + h * 128 + d] = f2bf(Of[of][v] * invl[v]);
            }
    };
    epilogue(Of0, l0_, 0);
    epilogue(Of1, l1_, 1);
}

// ---------------------------------------------------------------------------
extern "C" void kernel_launch(void* const* d_in, const int* in_sizes, int n_in,
                              void* d_out, int out_size, void* d_ws, size_t ws_size,
                              hipStream_t stream) {
    (void)in_sizes; (void)n_in; (void)out_size; (void)ws_size;
    const float* x   = (const float*)d_in[0];
    const int*   kq  = (const int*)d_in[1];
    const int*   vq  = (const int*)d_in[2];
    const float* ks  = (const float*)d_in[3];
    const float* vs  = (const float*)d_in[4];
    const float* Wq  = (const float*)d_in[5];
    const float* Wk  = (const float*)d_in[6];
    const float* Wv  = (const float*)d_in[7];
    const float* Wo  = (const float*)d_in[8];

    float* out  = (float*)d_out;
    float* y_o  = out;
    float* oktq = out + 4194304;
    float* ovtq = out + 37748736;
    float* oksc = out + 71303168;
    float* ovsc = out + 71565312;

    char* wsb = (char*)d_ws;
    u16* kcb = (u16*)(wsb);                       // 75.5 MB: [64][4608][128] bf16
    u16* vtb = (u16*)(wsb + 75497472);            // 75.5 MB: [64][128][4608] bf16
    u16* xb  = (u16*)(wsb + 150994944);           // 8 MB
    u16* wb  = (u16*)(wsb + 159383552);           // 8 MB (reused per GEMM)
    u16* qbf = (u16*)(wsb + 167772160);           // 8 MB
    u16* vnb = (u16*)(wsb + 176160768);           // 8 MB
    u16* ybf = (u16*)(wsb + 184549376);           // 8 MB

    const float rscale = 0.08838834764831845f;    // 1/sqrt(128)
    const int n8 = 2048 * 2048 / 8;

    prep_cache_kernel<<<4096, 256, 0, stream>>>(kq, vq, ks, vs, kcb, vtb,
                                                oktq, ovtq, oksc, ovsc);
    convert_kernel<<<2048, 256, 0, stream>>>(x, xb, 1.0f, n8);
    convert_kernel<<<2048, 256, 0, stream>>>(Wq, wb, rscale, n8);
    gemm_bf16_kernel<0><<<512, 128, 0, stream>>>(xb, wb, qbf);
    convert_kernel<<<2048, 256, 0, stream>>>(Wk, wb, 1.0f, n8);
    gemm_bf16_kernel<1><<<512, 128, 0, stream>>>(xb, wb, kcb);
    convert_kernel<<<2048, 256, 0, stream>>>(Wv, wb, 1.0f, n8);
    gemm_bf16_kernel<2><<<512, 128, 0, stream>>>(xb, wb, vnb);
    quant_new_kernel<<<512, 256, 0, stream>>>(kcb, vnb, vtb,
                                              oktq, ovtq, oksc, ovsc);
    attn_kernel<<<256, 256, 0, stream>>>(qbf, kcb, vtb, ybf);
    convert_kernel<<<2048, 256, 0, stream>>>(Wo, wb, 1.0f, n8);
    gemm_bf16_kernel<3><<<512, 128, 0, stream>>>(ybf, wb, y_o);
}

// Round 7
// 525.082 us; speedup vs baseline: 1.0720x; 1.0720x over previous
//
#include <hip/hip_runtime.h>
#include <hip/hip_fp16.h>

typedef float   f32x4   __attribute__((ext_vector_type(4)));
typedef float   f32x2   __attribute__((ext_vector_type(2)));
typedef float   f32x16  __attribute__((ext_vector_type(16)));
typedef short   short8v __attribute__((ext_vector_type(8)));
typedef unsigned short ushort8v __attribute__((ext_vector_type(8)));
typedef unsigned int   u32x4v __attribute__((ext_vector_type(4)));
typedef int     int2v   __attribute__((ext_vector_type(2)));
typedef unsigned int   u32;
typedef unsigned short u16;

#define DEVI static __device__ __forceinline__

DEVI u16 f2bf(float f) {
    u32 u = __builtin_bit_cast(u32, f);
    u += 0x7FFFu + ((u >> 16) & 1u);   // RNE (inputs finite)
    return (u16)(u >> 16);
}
DEVI float bf2f(u16 h) { return __builtin_bit_cast(float, (u32)h << 16); }

// async global->LDS, 16B per lane; lds ptr must be wave-uniform (lane*16 added by HW)
DEVI void gl_lds16(const u16* g, u16* l) {
    __builtin_amdgcn_global_load_lds(
        (const __attribute__((address_space(1))) u32*)(const void*)g,
        (__attribute__((address_space(3))) u32*)(void*)l, 16, 0, 0);
}

// ---------------------------------------------------------------------------
// convert f32 -> bf16 (optionally scaled). n8 = elements/8.
// ---------------------------------------------------------------------------
__global__ __launch_bounds__(256) void convert_kernel(
    const float* __restrict__ src, u16* __restrict__ dst, float scale, int n8) {
    int idx = blockIdx.x * 256 + threadIdx.x;
    if (idx >= n8) return;
    const float* p = src + (size_t)idx * 8;
    f32x4 a = *(const f32x4*)p, b = *(const f32x4*)(p + 4);
    ushort8v o;
    o[0]=f2bf(a[0]*scale); o[1]=f2bf(a[1]*scale); o[2]=f2bf(a[2]*scale); o[3]=f2bf(a[3]*scale);
    o[4]=f2bf(b[0]*scale); o[5]=f2bf(b[1]*scale); o[6]=f2bf(b[2]*scale); o[7]=f2bf(b[3]*scale);
    *(ushort8v*)(dst + (size_t)idx * 8) = o;
}

// ---------------------------------------------------------------------------
// prep_cache: dequant cache -> bf16 K rows (kcb rows 0..4095) + bf16 V^T cols
// 0..4095 + exact requant of window rows 512..4095. Grid 4096, 256 thr.
// ---------------------------------------------------------------------------
__global__ __launch_bounds__(256) void prep_cache_kernel(
    const int* __restrict__ kq, const int* __restrict__ vq,
    const float* __restrict__ ks, const float* __restrict__ vs,
    u16* __restrict__ kcb, u16* __restrict__ vt,
    float* __restrict__ oktq, float* __restrict__ ovtq,
    float* __restrict__ oksc, float* __restrict__ ovsc) {
    __shared__ u16 Vs[64][132];
    __shared__ float skL[64], svL[64];
    const int tid = threadIdx.x;
    const int bh = blockIdx.x >> 6, kt = blockIdx.x & 63;
    const int key0 = kt << 6;
    const size_t rowbase = (size_t)bh * 4096 + key0;
    if (tid < 64) { skL[tid] = ks[rowbase + tid]; svL[tid] = vs[rowbase + tid]; }
    __syncthreads();
    const int lane = tid & 63, w = tid >> 6;
    u32* kcw = (u32*)kcb;
    #pragma unroll 4
    for (int s = 0; s < 16; ++s) {
        const int key = s * 4 + w;
        const size_t row = rowbase + key;
        const float sk = skL[key], sv = svL[key];
        int2v kv = *(const int2v*)(kq + row * 128 + lane * 2);
        int2v vv = *(const int2v*)(vq + row * 128 + lane * 2);
        float kx0 = (float)kv[0] * sk, kx1 = (float)kv[1] * sk;
        float vx0 = (float)vv[0] * sv, vx1 = (float)vv[1] * sv;
        kcw[(size_t)(bh * 4608 + key0 + key) * 64 + lane] =
            (u32)f2bf(kx0) | ((u32)f2bf(kx1) << 16);
        *(u32*)&Vs[key][lane * 2] = (u32)f2bf(vx0) | ((u32)f2bf(vx1) << 16);
        float kam = fmaxf(fabsf(kx0), fabsf(kx1));
        float vam = fmaxf(fabsf(vx0), fabsf(vx1));
        #pragma unroll
        for (int off = 1; off < 64; off <<= 1) {
            kam = fmaxf(kam, __shfl_xor(kam, off, 64));
            vam = fmaxf(vam, __shfl_xor(vam, off, 64));
        }
        const int r = key0 + key;
        if (r >= 512) {
            const size_t orow = (size_t)bh * 4096 + (size_t)(r - 512);
            float kscale = fmaxf(kam / 127.0f, 1e-8f);
            float vscale = fmaxf(vam / 127.0f, 1e-8f);
            float kinv = 1.0f / kscale, vinv = 1.0f / vscale;
            f32x2 ko, vo;
            ko[0] = fminf(fmaxf(rintf(kx0 * kinv), -127.f), 127.f);
            ko[1] = fminf(fmaxf(rintf(kx1 * kinv), -127.f), 127.f);
            vo[0] = fminf(fmaxf(rintf(vx0 * vinv), -127.f), 127.f);
            vo[1] = fminf(fmaxf(rintf(vx1 * vinv), -127.f), 127.f);
            *(f32x2*)(oktq + orow * 128 + lane * 2) = ko;
            *(f32x2*)(ovtq + orow * 128 + lane * 2) = vo;
            if (lane == 0) {
                oksc[orow] = __half2float(__float2half(kscale));
                ovsc[orow] = __half2float(__float2half(vscale));
            }
        }
    }
    __syncthreads();
    const int d = tid >> 1, half = tid & 1;
    u16* obase = vt + ((size_t)bh * 128 + d) * 4608 + key0 + half * 32;
    #pragma unroll
    for (int c = 0; c < 4; ++c) {
        ushort8v tv;
        #pragma unroll
        for (int e = 0; e < 8; ++e) tv[e] = Vs[half * 32 + c * 8 + e][d];
        *(ushort8v*)(obase + c * 8) = tv;
    }
}

// ---------------------------------------------------------------------------
// bf16 GEMM  C[m][n] = sum_k A[m][k] * B[n][k]  (2048^3), BM=128 BN=64 BK=64,
// 256 thr (4 waves 2x2 of 64x32), gload_lds + XOR-swizzle + 2-phase dbuf.
// MODE 0: q bf16 head-split; 1: kcb bf16 rows 4096..; 2: vnb bf16 head-split;
// 3: f32 row-major.  (R5 known-good version.)
// ---------------------------------------------------------------------------
template <int MODE>
__global__ __launch_bounds__(256) void gemm_bf16_kernel(
    const u16* __restrict__ A, const u16* __restrict__ Bw,
    void* __restrict__ Cout) {
    __shared__ u16 As[2][128 * 64];
    __shared__ u16 Bs[2][64 * 64];
    const int tid = threadIdx.x, lane = tid & 63, w = tid >> 6;
    const int sid = (blockIdx.x & 7) * 64 + (blockIdx.x >> 3);  // XCD-chunked
    const int bm = sid & 15, bn = sid >> 4;
    const int m0 = bm * 128, n0 = bn * 64;
    const int wm = (w >> 1) * 64, wn = (w & 1) * 32;
    const int r16 = lane & 15, kb = lane >> 4;

    f32x4 acc[4][2] = {};

    auto stage = [&](int bi, int k0) {
        #pragma unroll
        for (int i = 0; i < 4; ++i) {
            int s = i * 256 + tid;
            int row = s >> 3, l = (s & 7) ^ (row & 7);
            gl_lds16(A + (size_t)(m0 + row) * 2048 + k0 + l * 8,
                     &As[bi][(i * 256 + (tid & ~63)) * 8]);
        }
        #pragma unroll
        for (int i = 0; i < 2; ++i) {
            int s = i * 256 + tid;
            int row = s >> 3, l = (s & 7) ^ (row & 7);
            gl_lds16(Bw + (size_t)(n0 + row) * 2048 + k0 + l * 8,
                     &Bs[bi][(i * 256 + (tid & ~63)) * 8]);
        }
    };

    stage(0, 0);
    __syncthreads();
    int cur = 0;
    for (int t = 0; t < 32; ++t) {
        if (t < 31) stage(cur ^ 1, (t + 1) * 64);
        short8v af[4][2], bf[2][2];
        #pragma unroll
        for (int mf = 0; mf < 4; ++mf) {
            int row = wm + mf * 16 + r16;
            #pragma unroll
            for (int ksv = 0; ksv < 2; ++ksv) {
                int blk = (ksv * 4 + kb) ^ (row & 7);
                af[mf][ksv] = __builtin_bit_cast(short8v,
                    *(const ushort8v*)&As[cur][row * 64 + blk * 8]);
            }
        }
        #pragma unroll
        for (int nf = 0; nf < 2; ++nf) {
            int row = wn + nf * 16 + r16;
            #pragma unroll
            for (int ksv = 0; ksv < 2; ++ksv) {
                int blk = (ksv * 4 + kb) ^ (row & 7);
                bf[nf][ksv] = __builtin_bit_cast(short8v,
                    *(const ushort8v*)&Bs[cur][row * 64 + blk * 8]);
            }
        }
        #pragma unroll
        for (int mf = 0; mf < 4; ++mf)
            #pragma unroll
            for (int nf = 0; nf < 2; ++nf)
                #pragma unroll
                for (int ksv = 0; ksv < 2; ++ksv)
                    acc[mf][nf] = __builtin_amdgcn_mfma_f32_16x16x32_bf16(
                        af[mf][ksv], bf[nf][ksv], acc[mf][nf], 0, 0, 0);
        __syncthreads();
        cur ^= 1;
    }

    #pragma unroll
    for (int mf = 0; mf < 4; ++mf)
        #pragma unroll
        for (int nf = 0; nf < 2; ++nf)
            #pragma unroll
            for (int v = 0; v < 4; ++v) {
                int mg = m0 + wm + mf * 16 + kb * 4 + v;
                int ng = n0 + wn + nf * 16 + r16;
                float val = acc[mf][nf][v];
                if (MODE == 0 || MODE == 2) {
                    ((u16*)Cout)[(((size_t)(mg >> 9) * 16 + (ng >> 7)) * 512 +
                                  (mg & 511)) * 128 + (ng & 127)] = f2bf(val);
                } else if (MODE == 1) {
                    size_t bh = (size_t)(mg >> 9) * 16 + (ng >> 7);
                    ((u16*)Cout)[(bh * 4608 + 4096 + (mg & 511)) * 128 + (ng & 127)] = f2bf(val);
                } else {
                    ((float*)Cout)[(size_t)mg * 2048 + ng] = val;
                }
            }
}

// ---------------------------------------------------------------------------
// quant_new: quantize new K/V rows + V^T cols 4096..4607. Grid 512, 256 thr.
// ---------------------------------------------------------------------------
__global__ __launch_bounds__(256) void quant_new_kernel(
    const u16* __restrict__ kcb, const u16* __restrict__ vnb,
    u16* __restrict__ vt,
    float* __restrict__ oktq, float* __restrict__ ovtq,
    float* __restrict__ oksc, float* __restrict__ ovsc) {
    __shared__ u16 Vs[64][132];
    const int tid = threadIdx.x;
    const int bh = blockIdx.x >> 3, kt = blockIdx.x & 7;
    const int i0 = kt << 6;
    const int lane = tid & 63, w = tid >> 6;
    #pragma unroll 4
    for (int s = 0; s < 16; ++s) {
        const int key = s * 4 + w;
        const int i = i0 + key;
        u32 ku = *(const u32*)(kcb + ((size_t)bh * 4608 + 4096 + i) * 128 + lane * 2);
        u32 vu = *(const u32*)(vnb + ((size_t)bh * 512 + i) * 128 + lane * 2);
        float kx0 = bf2f((u16)ku), kx1 = bf2f((u16)(ku >> 16));
        float vx0 = bf2f((u16)vu), vx1 = bf2f((u16)(vu >> 16));
        *(u32*)&Vs[key][lane * 2] = vu;
        float kam = fmaxf(fabsf(kx0), fabsf(kx1));
        float vam = fmaxf(fabsf(vx0), fabsf(vx1));
        #pragma unroll
        for (int off = 1; off < 64; off <<= 1) {
            kam = fmaxf(kam, __shfl_xor(kam, off, 64));
            vam = fmaxf(vam, __shfl_xor(vam, off, 64));
        }
        float kscale = fmaxf(kam / 127.0f, 1e-8f);
        float vscale = fmaxf(vam / 127.0f, 1e-8f);
        float kinv = 1.0f / kscale, vinv = 1.0f / vscale;
        const size_t orow = (size_t)bh * 4096 + 3584 + i;
        f32x2 ko, vo;
        ko[0] = fminf(fmaxf(rintf(kx0 * kinv), -127.f), 127.f);
        ko[1] = fminf(fmaxf(rintf(kx1 * kinv), -127.f), 127.f);
        vo[0] = fminf(fmaxf(rintf(vx0 * vinv), -127.f), 127.f);
        vo[1] = fminf(fmaxf(rintf(vx1 * vinv), -127.f), 127.f);
        *(f32x2*)(oktq + orow * 128 + lane * 2) = ko;
        *(f32x2*)(ovtq + orow * 128 + lane * 2) = vo;
        if (lane == 0) {
            oksc[orow] = __half2float(__float2half(kscale));
            ovsc[orow] = __half2float(__float2half(vscale));
        }
    }
    __syncthreads();
    const int d = tid >> 1, half = tid & 1;
    u16* obase = vt + ((size_t)bh * 128 + d) * 4608 + 4096 + i0 + half * 32;
    #pragma unroll
    for (int c = 0; c < 4; ++c) {
        ushort8v tv;
        #pragma unroll
        for (int e = 0; e < 8; ++e) tv[e] = Vs[half * 32 + c * 8 + e][d];
        *(ushort8v*)(obase + c * 8) = tv;
    }
}

// ---------------------------------------------------------------------------
// attn: 512 blocks = (b,h) x 8 q-tiles of 64 rows; 2 waves x 32 q-rows.
// 32x32x16 MFMA: swapped QK^T (lane q = lane&31), in-register softmax,
// P->PV fragment via cvt_pk + permlane32_swap (NO P LDS round-trip).
// LDS 64KB (K/V dbuf) -> 2 blocks/CU. Defer-max THR=8.
// ---------------------------------------------------------------------------
__global__ __launch_bounds__(128, 2) void attn_kernel(
    const u16* __restrict__ qb, const u16* __restrict__ kcb,
    const u16* __restrict__ vt, u16* __restrict__ yb) {
    __shared__ u16 Ks[2][64 * 128];
    __shared__ u16 Vl[2][128 * 64];

    const int tid = threadIdx.x, lane = tid & 63, w = tid >> 6;
    const int p = blockIdx.x;
    const int bh = ((p >> 6) << 3) | (p & 7);   // p%8 == bh%8 -> same XCD per bh
    const int qt = (p >> 3) & 7;
    const int b = bh >> 4, h = bh & 15;
    const int q31 = lane & 31, hi = lane >> 5;

    // Q fragments (B-operand): col=q31, k(d) = s*16 + hi*8 + e
    const u16* qp = qb + ((size_t)bh * 512 + qt * 64 + w * 32 + q31) * 128 + hi * 8;
    short8v qf[8];
    #pragma unroll
    for (int s = 0; s < 8; ++s)
        qf[s] = __builtin_bit_cast(short8v, *(const ushort8v*)(qp + s * 16));

    f32x16 O[4] = {};
    float m_i = -3.0e38f, l_i = 0.f;    // per-lane: q-row = q31

    const size_t kbase = (size_t)bh * 4608 * 128;
    const size_t vbase = (size_t)bh * 128 * 4608;
    const int nt = 65 + qt;

    auto STAGE = [&](int bi, int kt) {
        #pragma unroll
        for (int i = 0; i < 8; ++i) {
            int s = i * 128 + tid;
            int row = s >> 4, l = (s & 15) ^ (row & 7);
            gl_lds16(kcb + kbase + (size_t)(kt * 64 + row) * 128 + l * 8,
                     &Ks[bi][(i * 128 + (tid & ~63)) * 8]);
        }
        #pragma unroll
        for (int i = 0; i < 8; ++i) {
            int s = i * 128 + tid;
            int row = s >> 3, l = (s & 7) ^ (row & 7);
            gl_lds16(vt + vbase + (size_t)row * 4608 + kt * 64 + l * 8,
                     &Vl[bi][(i * 128 + (tid & ~63)) * 8]);
        }
    };

    STAGE(0, 0);
    __syncthreads();
    int cur = 0;
    for (int kt = 0; kt < nt; ++kt) {
        if (kt + 1 < nt) STAGE(cur ^ 1, kt + 1);

        // S^T tiles: S[t] reg r = S[key = t*32 + (r&3)+8*(r>>2)+4*hi][q=q31]
        f32x16 S[2] = {};
        __builtin_amdgcn_s_setprio(1);
        #pragma unroll
        for (int s = 0; s < 8; ++s) {
            #pragma unroll
            for (int t = 0; t < 2; ++t) {
                int krow = t * 32 + q31;
                int blk = (2 * s + hi) ^ (krow & 7);
                short8v kf = __builtin_bit_cast(short8v,
                    *(const ushort8v*)&Ks[cur][krow * 128 + blk * 8]);
                S[t] = __builtin_amdgcn_mfma_f32_32x32x16_bf16(kf, qf[s], S[t], 0, 0, 0);
            }
        }
        __builtin_amdgcn_s_setprio(0);

        if (kt >= 64) {  // causal mask within the new segment
            const int kb0 = (kt - 64) * 64 + 4 * hi;
            const int qn = qt * 64 + w * 32 + q31;
            #pragma unroll
            for (int r = 0; r < 16; ++r) {
                int koff = kb0 + (r & 3) + 8 * (r >> 2);
                if (koff > qn)      S[0][r] = -3.0e38f;
                if (koff + 32 > qn) S[1][r] = -3.0e38f;
            }
        }

        // row max: local tree over 32 regs + 1 shuffle across the hi halves
        float mx = fmaxf(S[0][0], S[1][0]);
        #pragma unroll
        for (int r = 1; r < 16; ++r) mx = fmaxf(mx, fmaxf(S[0][r], S[1][r]));
        mx = fmaxf(mx, __shfl_xor(mx, 32, 64));

        // defer-max: rescale only when some row grew past m+8
        if (__ballot(mx > m_i + 8.f)) {
            float mnew = fmaxf(m_i, mx);
            float alpha = __expf(m_i - mnew);
            m_i = mnew;
            l_i *= alpha;
            #pragma unroll
            for (int r = 0; r < 16; ++r) {
                float ar = __shfl(alpha, (r & 3) + 8 * (r >> 2) + 4 * hi, 64);
                O[0][r] *= ar; O[1][r] *= ar; O[2][r] *= ar; O[3][r] *= ar;
            }
        }
        // P = exp(S - m), per-lane partial l
        #pragma unroll
        for (int r = 0; r < 16; ++r) {
            S[0][r] = __expf(S[0][r] - m_i); l_i += S[0][r];
            S[1][r] = __expf(S[1][r] - m_i); l_i += S[1][r];
        }

        // O += P V : per k-step j build P A-frag in-register (cvt_pk + permlane)
        __builtin_amdgcn_s_setprio(1);
        #pragma unroll
        for (int j = 0; j < 4; ++j) {
            const int t = j >> 1, r0 = 8 * (j & 1);
            u32 a0, a1, b0, b1;
            asm("v_cvt_pk_bf16_f32 %0, %1, %2" : "=v"(a0) : "v"(S[t][r0+0]), "v"(S[t][r0+1]));
            asm("v_cvt_pk_bf16_f32 %0, %1, %2" : "=v"(a1) : "v"(S[t][r0+2]), "v"(S[t][r0+3]));
            asm("v_cvt_pk_bf16_f32 %0, %1, %2" : "=v"(b0) : "v"(S[t][r0+4]), "v"(S[t][r0+5]));
            asm("v_cvt_pk_bf16_f32 %0, %1, %2" : "=v"(b1) : "v"(S[t][r0+6]), "v"(S[t][r0+7]));
            asm("v_permlane32_swap_b32 %0, %1" : "+v"(a0), "+v"(b0));
            asm("v_permlane32_swap_b32 %0, %1" : "+v"(a1), "+v"(b1));
            u32x4v pw = {a0, a1, b0, b1};
            short8v pf = __builtin_bit_cast(short8v, pw);
            #pragma unroll
            for (int od = 0; od < 4; ++od) {
                int vrow = od * 32 + q31;
                int blk = (2 * j + hi) ^ (vrow & 7);
                short8v vf = __builtin_bit_cast(short8v,
                    *(const ushort8v*)&Vl[cur][vrow * 64 + blk * 8]);
                O[od] = __builtin_amdgcn_mfma_f32_32x32x16_bf16(pf, vf, O[od], 0, 0, 0);
            }
        }
        __builtin_amdgcn_s_setprio(0);

        __syncthreads();
        cur ^= 1;
    }

    // epilogue: l reduce across hi halves; per-reg q-row gather of 1/l
    float lt = l_i + __shfl_xor(l_i, 32, 64);
    float linv = 1.0f / lt;
    #pragma unroll
    for (int r = 0; r < 16; ++r) {
        int qoff = (r & 3) + 8 * (r >> 2) + 4 * hi;
        float ir = __shfl(linv, qoff, 64);
        int qrow = qt * 64 + w * 32 + qoff;
        size_t rb = (size_t)(b * 512 + qrow) * 2048 + h * 128 + q31;
        yb[rb +  0] = f2bf(O[0][r] * ir);
        yb[rb + 32] = f2bf(O[1][r] * ir);
        yb[rb + 64] = f2bf(O[2][r] * ir);
        yb[rb + 96] = f2bf(O[3][r] * ir);
    }
}

// ---------------------------------------------------------------------------
extern "C" void kernel_launch(void* const* d_in, const int* in_sizes, int n_in,
                              void* d_out, int out_size, void* d_ws, size_t ws_size,
                              hipStream_t stream) {
    (void)in_sizes; (void)n_in; (void)out_size; (void)ws_size;
    const float* x   = (const float*)d_in[0];
    const int*   kq  = (const int*)d_in[1];
    const int*   vq  = (const int*)d_in[2];
    const float* ks  = (const float*)d_in[3];
    const float* vs  = (const float*)d_in[4];
    const float* Wq  = (const float*)d_in[5];
    const float* Wk  = (const float*)d_in[6];
    const float* Wv  = (const float*)d_in[7];
    const float* Wo  = (const float*)d_in[8];

    float* out  = (float*)d_out;
    float* y_o  = out;
    float* oktq = out + 4194304;
    float* ovtq = out + 37748736;
    float* oksc = out + 71303168;
    float* ovsc = out + 71565312;

    char* wsb = (char*)d_ws;
    u16* kcb = (u16*)(wsb);                       // 75.5 MB: [64][4608][128] bf16
    u16* vtb = (u16*)(wsb + 75497472);            // 75.5 MB: [64][128][4608] bf16
    u16* xb  = (u16*)(wsb + 150994944);           // 8 MB
    u16* wb  = (u16*)(wsb + 159383552);           // 8 MB (reused per GEMM)
    u16* qbf = (u16*)(wsb + 167772160);           // 8 MB
    u16* vnb = (u16*)(wsb + 176160768);           // 8 MB
    u16* ybf = (u16*)(wsb + 184549376);           // 8 MB

    const float rscale = 0.08838834764831845f;    // 1/sqrt(128)
    const int n8 = 2048 * 2048 / 8;

    prep_cache_kernel<<<4096, 256, 0, stream>>>(kq, vq, ks, vs, kcb, vtb,
                                                oktq, ovtq, oksc, ovsc);
    convert_kernel<<<2048, 256, 0, stream>>>(x, xb, 1.0f, n8);
    convert_kernel<<<2048, 256, 0, stream>>>(Wq, wb, rscale, n8);
    gemm_bf16_kernel<0><<<512, 256, 0, stream>>>(xb, wb, qbf);
    convert_kernel<<<2048, 256, 0, stream>>>(Wk, wb, 1.0f, n8);
    gemm_bf16_kernel<1><<<512, 256, 0, stream>>>(xb, wb, kcb);
    convert_kernel<<<2048, 256, 0, stream>>>(Wv, wb, 1.0f, n8);
    gemm_bf16_kernel<2><<<512, 256, 0, stream>>>(xb, wb, vnb);
    quant_new_kernel<<<512, 256, 0, stream>>>(kcb, vnb, vtb,
                                              oktq, ovtq, oksc, ovsc);
    attn_kernel<<<512, 128, 0, stream>>>(qbf, kcb, vtb, ybf);
    convert_kernel<<<2048, 256, 0, stream>>>(Wo, wb, 1.0f, n8);
    gemm_bf16_kernel<3><<<512, 256, 0, stream>>>(ybf, wb, y_o);
}

// Round 8
// 420.061 us; speedup vs baseline: 1.3400x; 1.2500x over previous
//
#include <hip/hip_runtime.h>
#include <hip/hip_fp16.h>

typedef float   f32x4   __attribute__((ext_vector_type(4)));
typedef float   f32x2   __attribute__((ext_vector_type(2)));
typedef float   f32x16  __attribute__((ext_vector_type(16)));
typedef short   short8v __attribute__((ext_vector_type(8)));
typedef unsigned short ushort8v __attribute__((ext_vector_type(8)));
typedef unsigned int   u32x4v __attribute__((ext_vector_type(4)));
typedef int     int2v   __attribute__((ext_vector_type(2)));
typedef unsigned int   u32;
typedef unsigned short u16;

#define DEVI static __device__ __forceinline__

DEVI u16 f2bf(float f) {
    u32 u = __builtin_bit_cast(u32, f);
    u += 0x7FFFu + ((u >> 16) & 1u);   // RNE (inputs finite)
    return (u16)(u >> 16);
}
DEVI float bf2f(u16 h) { return __builtin_bit_cast(float, (u32)h << 16); }

// async global->LDS, 16B per lane; lds ptr must be wave-uniform (lane*16 added by HW)
DEVI void gl_lds16(const u16* g, u16* l) {
    __builtin_amdgcn_global_load_lds(
        (const __attribute__((address_space(1))) u32*)(const void*)g,
        (__attribute__((address_space(3))) u32*)(void*)l, 16, 0, 0);
}

// ---------------------------------------------------------------------------
// convert f32 -> bf16 (optionally scaled). n8 = elements/8.
// ---------------------------------------------------------------------------
__global__ __launch_bounds__(256) void convert_kernel(
    const float* __restrict__ src, u16* __restrict__ dst, float scale, int n8) {
    int idx = blockIdx.x * 256 + threadIdx.x;
    if (idx >= n8) return;
    const float* p = src + (size_t)idx * 8;
    f32x4 a = *(const f32x4*)p, b = *(const f32x4*)(p + 4);
    ushort8v o;
    o[0]=f2bf(a[0]*scale); o[1]=f2bf(a[1]*scale); o[2]=f2bf(a[2]*scale); o[3]=f2bf(a[3]*scale);
    o[4]=f2bf(b[0]*scale); o[5]=f2bf(b[1]*scale); o[6]=f2bf(b[2]*scale); o[7]=f2bf(b[3]*scale);
    *(ushort8v*)(dst + (size_t)idx * 8) = o;
}

// ---------------------------------------------------------------------------
// prep_cache: dequant cache -> bf16 K rows (kcb rows 0..4095) + bf16 V^T cols
// 0..4095 + exact requant of window rows 512..4095. Grid 4096, 256 thr.
// ---------------------------------------------------------------------------
__global__ __launch_bounds__(256) void prep_cache_kernel(
    const int* __restrict__ kq, const int* __restrict__ vq,
    const float* __restrict__ ks, const float* __restrict__ vs,
    u16* __restrict__ kcb, u16* __restrict__ vt,
    float* __restrict__ oktq, float* __restrict__ ovtq,
    float* __restrict__ oksc, float* __restrict__ ovsc) {
    __shared__ u16 Vs[64][132];
    __shared__ float skL[64], svL[64];
    const int tid = threadIdx.x;
    const int bh = blockIdx.x >> 6, kt = blockIdx.x & 63;
    const int key0 = kt << 6;
    const size_t rowbase = (size_t)bh * 4096 + key0;
    if (tid < 64) { skL[tid] = ks[rowbase + tid]; svL[tid] = vs[rowbase + tid]; }
    __syncthreads();
    const int lane = tid & 63, w = tid >> 6;
    u32* kcw = (u32*)kcb;
    #pragma unroll 4
    for (int s = 0; s < 16; ++s) {
        const int key = s * 4 + w;
        const size_t row = rowbase + key;
        const float sk = skL[key], sv = svL[key];
        int2v kv = *(const int2v*)(kq + row * 128 + lane * 2);
        int2v vv = *(const int2v*)(vq + row * 128 + lane * 2);
        float kx0 = (float)kv[0] * sk, kx1 = (float)kv[1] * sk;
        float vx0 = (float)vv[0] * sv, vx1 = (float)vv[1] * sv;
        kcw[(size_t)(bh * 4608 + key0 + key) * 64 + lane] =
            (u32)f2bf(kx0) | ((u32)f2bf(kx1) << 16);
        *(u32*)&Vs[key][lane * 2] = (u32)f2bf(vx0) | ((u32)f2bf(vx1) << 16);
        float kam = fmaxf(fabsf(kx0), fabsf(kx1));
        float vam = fmaxf(fabsf(vx0), fabsf(vx1));
        #pragma unroll
        for (int off = 1; off < 64; off <<= 1) {
            kam = fmaxf(kam, __shfl_xor(kam, off, 64));
            vam = fmaxf(vam, __shfl_xor(vam, off, 64));
        }
        const int r = key0 + key;
        if (r >= 512) {
            const size_t orow = (size_t)bh * 4096 + (size_t)(r - 512);
            float kscale = fmaxf(kam / 127.0f, 1e-8f);
            float vscale = fmaxf(vam / 127.0f, 1e-8f);
            float kinv = 1.0f / kscale, vinv = 1.0f / vscale;
            f32x2 ko, vo;
            ko[0] = fminf(fmaxf(rintf(kx0 * kinv), -127.f), 127.f);
            ko[1] = fminf(fmaxf(rintf(kx1 * kinv), -127.f), 127.f);
            vo[0] = fminf(fmaxf(rintf(vx0 * vinv), -127.f), 127.f);
            vo[1] = fminf(fmaxf(rintf(vx1 * vinv), -127.f), 127.f);
            *(f32x2*)(oktq + orow * 128 + lane * 2) = ko;
            *(f32x2*)(ovtq + orow * 128 + lane * 2) = vo;
            if (lane == 0) {
                oksc[orow] = __half2float(__float2half(kscale));
                ovsc[orow] = __half2float(__float2half(vscale));
            }
        }
    }
    __syncthreads();
    const int d = tid >> 1, half = tid & 1;
    u16* obase = vt + ((size_t)bh * 128 + d) * 4608 + key0 + half * 32;
    #pragma unroll
    for (int c = 0; c < 4; ++c) {
        ushort8v tv;
        #pragma unroll
        for (int e = 0; e < 8; ++e) tv[e] = Vs[half * 32 + c * 8 + e][d];
        *(ushort8v*)(obase + c * 8) = tv;
    }
}

// ---------------------------------------------------------------------------
// fused QKV GEMM: C[m][n] = sum_k A[m][k]*W3[n][k], M=K=2048, N=6144.
// Grid 1536, 256 thr (4 waves 2x2 of 64x32), BM=128 BN=64 BK=64.
// Output routed: n<2048 -> qbf head-split; <4096 -> kcb rows 4096..; else vnb.
// ---------------------------------------------------------------------------
__global__ __launch_bounds__(256) void gemm_qkv_kernel(
    const u16* __restrict__ A, const u16* __restrict__ Bw,
    u16* __restrict__ qbf, u16* __restrict__ kcb, u16* __restrict__ vnb) {
    __shared__ u16 As[2][128 * 64];
    __shared__ u16 Bs[2][64 * 64];
    const int tid = threadIdx.x, lane = tid & 63, w = tid >> 6;
    const int sid = (blockIdx.x & 7) * 192 + (blockIdx.x >> 3);  // XCD-chunked
    const int bm = sid & 15, bn = sid >> 4;
    const int m0 = bm * 128, n0 = bn * 64;
    const int wm = (w >> 1) * 64, wn = (w & 1) * 32;
    const int r16 = lane & 15, kb = lane >> 4;

    f32x4 acc[4][2] = {};

    auto stage = [&](int bi, int k0) {
        #pragma unroll
        for (int i = 0; i < 4; ++i) {
            int s = i * 256 + tid;
            int row = s >> 3, l = (s & 7) ^ (row & 7);
            gl_lds16(A + (size_t)(m0 + row) * 2048 + k0 + l * 8,
                     &As[bi][(i * 256 + (tid & ~63)) * 8]);
        }
        #pragma unroll
        for (int i = 0; i < 2; ++i) {
            int s = i * 256 + tid;
            int row = s >> 3, l = (s & 7) ^ (row & 7);
            gl_lds16(Bw + (size_t)(n0 + row) * 2048 + k0 + l * 8,
                     &Bs[bi][(i * 256 + (tid & ~63)) * 8]);
        }
    };

    stage(0, 0);
    __syncthreads();
    int cur = 0;
    for (int t = 0; t < 32; ++t) {
        if (t < 31) stage(cur ^ 1, (t + 1) * 64);
        short8v af[4][2], bf[2][2];
        #pragma unroll
        for (int mf = 0; mf < 4; ++mf) {
            int row = wm + mf * 16 + r16;
            #pragma unroll
            for (int ksv = 0; ksv < 2; ++ksv) {
                int blk = (ksv * 4 + kb) ^ (row & 7);
                af[mf][ksv] = __builtin_bit_cast(short8v,
                    *(const ushort8v*)&As[cur][row * 64 + blk * 8]);
            }
        }
        #pragma unroll
        for (int nf = 0; nf < 2; ++nf) {
            int row = wn + nf * 16 + r16;
            #pragma unroll
            for (int ksv = 0; ksv < 2; ++ksv) {
                int blk = (ksv * 4 + kb) ^ (row & 7);
                bf[nf][ksv] = __builtin_bit_cast(short8v,
                    *(const ushort8v*)&Bs[cur][row * 64 + blk * 8]);
            }
        }
        #pragma unroll
        for (int mf = 0; mf < 4; ++mf)
            #pragma unroll
            for (int nf = 0; nf < 2; ++nf)
                #pragma unroll
                for (int ksv = 0; ksv < 2; ++ksv)
                    acc[mf][nf] = __builtin_amdgcn_mfma_f32_16x16x32_bf16(
                        af[mf][ksv], bf[nf][ksv], acc[mf][nf], 0, 0, 0);
        __syncthreads();
        cur ^= 1;
    }

    #pragma unroll
    for (int mf = 0; mf < 4; ++mf)
        #pragma unroll
        for (int nf = 0; nf < 2; ++nf)
            #pragma unroll
            for (int v = 0; v < 4; ++v) {
                int mg = m0 + wm + mf * 16 + kb * 4 + v;
                int ng = n0 + wn + nf * 16 + r16;
                int nb = ng >> 11, ngl = ng & 2047;
                u16 val = f2bf(acc[mf][nf][v]);
                if (nb == 1) {
                    size_t bh = (size_t)(mg >> 9) * 16 + (ngl >> 7);
                    kcb[(bh * 4608 + 4096 + (mg & 511)) * 128 + (ngl & 127)] = val;
                } else {
                    u16* dst = (nb == 0) ? qbf : vnb;
                    dst[(((size_t)(mg >> 9) * 16 + (ngl >> 7)) * 512 +
                         (mg & 511)) * 128 + (ngl & 127)] = val;
                }
            }
}

// ---------------------------------------------------------------------------
// W_o GEMM: C f32 row-major. (R5 known-good 4-wave version.)
// ---------------------------------------------------------------------------
__global__ __launch_bounds__(256) void gemm_wo_kernel(
    const u16* __restrict__ A, const u16* __restrict__ Bw,
    float* __restrict__ Cout) {
    __shared__ u16 As[2][128 * 64];
    __shared__ u16 Bs[2][64 * 64];
    const int tid = threadIdx.x, lane = tid & 63, w = tid >> 6;
    const int sid = (blockIdx.x & 7) * 64 + (blockIdx.x >> 3);
    const int bm = sid & 15, bn = sid >> 4;
    const int m0 = bm * 128, n0 = bn * 64;
    const int wm = (w >> 1) * 64, wn = (w & 1) * 32;
    const int r16 = lane & 15, kb = lane >> 4;

    f32x4 acc[4][2] = {};

    auto stage = [&](int bi, int k0) {
        #pragma unroll
        for (int i = 0; i < 4; ++i) {
            int s = i * 256 + tid;
            int row = s >> 3, l = (s & 7) ^ (row & 7);
            gl_lds16(A + (size_t)(m0 + row) * 2048 + k0 + l * 8,
                     &As[bi][(i * 256 + (tid & ~63)) * 8]);
        }
        #pragma unroll
        for (int i = 0; i < 2; ++i) {
            int s = i * 256 + tid;
            int row = s >> 3, l = (s & 7) ^ (row & 7);
            gl_lds16(Bw + (size_t)(n0 + row) * 2048 + k0 + l * 8,
                     &Bs[bi][(i * 256 + (tid & ~63)) * 8]);
        }
    };

    stage(0, 0);
    __syncthreads();
    int cur = 0;
    for (int t = 0; t < 32; ++t) {
        if (t < 31) stage(cur ^ 1, (t + 1) * 64);
        short8v af[4][2], bf[2][2];
        #pragma unroll
        for (int mf = 0; mf < 4; ++mf) {
            int row = wm + mf * 16 + r16;
            #pragma unroll
            for (int ksv = 0; ksv < 2; ++ksv) {
                int blk = (ksv * 4 + kb) ^ (row & 7);
                af[mf][ksv] = __builtin_bit_cast(short8v,
                    *(const ushort8v*)&As[cur][row * 64 + blk * 8]);
            }
        }
        #pragma unroll
        for (int nf = 0; nf < 2; ++nf) {
            int row = wn + nf * 16 + r16;
            #pragma unroll
            for (int ksv = 0; ksv < 2; ++ksv) {
                int blk = (ksv * 4 + kb) ^ (row & 7);
                bf[nf][ksv] = __builtin_bit_cast(short8v,
                    *(const ushort8v*)&Bs[cur][row * 64 + blk * 8]);
            }
        }
        #pragma unroll
        for (int mf = 0; mf < 4; ++mf)
            #pragma unroll
            for (int nf = 0; nf < 2; ++nf)
                #pragma unroll
                for (int ksv = 0; ksv < 2; ++ksv)
                    acc[mf][nf] = __builtin_amdgcn_mfma_f32_16x16x32_bf16(
                        af[mf][ksv], bf[nf][ksv], acc[mf][nf], 0, 0, 0);
        __syncthreads();
        cur ^= 1;
    }

    #pragma unroll
    for (int mf = 0; mf < 4; ++mf)
        #pragma unroll
        for (int nf = 0; nf < 2; ++nf)
            #pragma unroll
            for (int v = 0; v < 4; ++v) {
                int mg = m0 + wm + mf * 16 + kb * 4 + v;
                int ng = n0 + wn + nf * 16 + r16;
                Cout[(size_t)mg * 2048 + ng] = acc[mf][nf][v];
            }
}

// ---------------------------------------------------------------------------
// quant_new: quantize new K/V rows + V^T cols 4096..4607. Grid 512, 256 thr.
// ---------------------------------------------------------------------------
__global__ __launch_bounds__(256) void quant_new_kernel(
    const u16* __restrict__ kcb, const u16* __restrict__ vnb,
    u16* __restrict__ vt,
    float* __restrict__ oktq, float* __restrict__ ovtq,
    float* __restrict__ oksc, float* __restrict__ ovsc) {
    __shared__ u16 Vs[64][132];
    const int tid = threadIdx.x;
    const int bh = blockIdx.x >> 3, kt = blockIdx.x & 7;
    const int i0 = kt << 6;
    const int lane = tid & 63, w = tid >> 6;
    #pragma unroll 4
    for (int s = 0; s < 16; ++s) {
        const int key = s * 4 + w;
        const int i = i0 + key;
        u32 ku = *(const u32*)(kcb + ((size_t)bh * 4608 + 4096 + i) * 128 + lane * 2);
        u32 vu = *(const u32*)(vnb + ((size_t)bh * 512 + i) * 128 + lane * 2);
        float kx0 = bf2f((u16)ku), kx1 = bf2f((u16)(ku >> 16));
        float vx0 = bf2f((u16)vu), vx1 = bf2f((u16)(vu >> 16));
        *(u32*)&Vs[key][lane * 2] = vu;
        float kam = fmaxf(fabsf(kx0), fabsf(kx1));
        float vam = fmaxf(fabsf(vx0), fabsf(vx1));
        #pragma unroll
        for (int off = 1; off < 64; off <<= 1) {
            kam = fmaxf(kam, __shfl_xor(kam, off, 64));
            vam = fmaxf(vam, __shfl_xor(vam, off, 64));
        }
        float kscale = fmaxf(kam / 127.0f, 1e-8f);
        float vscale = fmaxf(vam / 127.0f, 1e-8f);
        float kinv = 1.0f / kscale, vinv = 1.0f / vscale;
        const size_t orow = (size_t)bh * 4096 + 3584 + i;
        f32x2 ko, vo;
        ko[0] = fminf(fmaxf(rintf(kx0 * kinv), -127.f), 127.f);
        ko[1] = fminf(fmaxf(rintf(kx1 * kinv), -127.f), 127.f);
        vo[0] = fminf(fmaxf(rintf(vx0 * vinv), -127.f), 127.f);
        vo[1] = fminf(fmaxf(rintf(vx1 * vinv), -127.f), 127.f);
        *(f32x2*)(oktq + orow * 128 + lane * 2) = ko;
        *(f32x2*)(ovtq + orow * 128 + lane * 2) = vo;
        if (lane == 0) {
            oksc[orow] = __half2float(__float2half(kscale));
            ovsc[orow] = __half2float(__float2half(vscale));
        }
    }
    __syncthreads();
    const int d = tid >> 1, half = tid & 1;
    u16* obase = vt + ((size_t)bh * 128 + d) * 4608 + 4096 + i0 + half * 32;
    #pragma unroll
    for (int c = 0; c < 4; ++c) {
        ushort8v tv;
        #pragma unroll
        for (int e = 0; e < 8; ++e) tv[e] = Vs[half * 32 + c * 8 + e][d];
        *(ushort8v*)(obase + c * 8) = tv;
    }
}

// ---------------------------------------------------------------------------
// attn split-K: 512 blocks = 64 bh x 4 q-tiles(128) x 2 key-splits.
// 4 waves x 32 q-rows; 32x32x16 MFMA; swapped QK^T; in-register softmax;
// cvt_pk+permlane P fragments; partial (m,l,O bf16) out. 8 waves/CU.
// ---------------------------------------------------------------------------
__global__ __launch_bounds__(256, 2) void attn_kernel(
    const u16* __restrict__ qb, const u16* __restrict__ kcb,
    const u16* __restrict__ vt, u16* __restrict__ Op0, u16* __restrict__ Op1,
    float* __restrict__ mlp) {
    __shared__ u16 Ks[2][64 * 128];
    __shared__ u16 Vl[2][128 * 64];

    const int tid = threadIdx.x, lane = tid & 63, w = tid >> 6;
    const int p = blockIdx.x;
    const int xcd = p & 7, i = p >> 3;
    const int qt2 = i & 3, sp = (i >> 2) & 1;
    const int bh = ((i >> 3) << 3) | xcd;      // bh%8 == xcd
    const int q31 = lane & 31, hi = lane >> 5;
    const int qrow = qt2 * 128 + w * 32 + q31;

    const u16* qp = qb + ((size_t)bh * 512 + qrow) * 128 + hi * 8;
    short8v qf[8];
    #pragma unroll
    for (int s = 0; s < 8; ++s)
        qf[s] = __builtin_bit_cast(short8v, *(const ushort8v*)(qp + s * 16));

    f32x16 O[4] = {};
    float m_i = -3.0e38f, l_i = 0.f;

    const size_t kbase = (size_t)bh * 4608 * 128;
    const size_t vbase = (size_t)bh * 128 * 4608;
    const int ktA = sp ? 32 : 0;
    const int ktB = sp ? (66 + 2 * qt2) : 32;

    auto STAGE = [&](int bi, int kt) {
        #pragma unroll
        for (int ii = 0; ii < 4; ++ii) {
            int s = ii * 256 + tid;
            int row = s >> 4, l = (s & 15) ^ (row & 7);
            gl_lds16(kcb + kbase + (size_t)(kt * 64 + row) * 128 + l * 8,
                     &Ks[bi][(ii * 256 + (tid & ~63)) * 8]);
        }
        #pragma unroll
        for (int ii = 0; ii < 4; ++ii) {
            int s = ii * 256 + tid;
            int row = s >> 3, l = (s & 7) ^ (row & 7);
            gl_lds16(vt + vbase + (size_t)row * 4608 + kt * 64 + l * 8,
                     &Vl[bi][(ii * 256 + (tid & ~63)) * 8]);
        }
    };

    STAGE(0, ktA);
    __syncthreads();
    int cur = 0;
    for (int kt = ktA; kt < ktB; ++kt) {
        if (kt + 1 < ktB) STAGE(cur ^ 1, kt + 1);

        f32x16 S[2] = {};
        __builtin_amdgcn_s_setprio(1);
        #pragma unroll
        for (int s = 0; s < 8; ++s) {
            #pragma unroll
            for (int t = 0; t < 2; ++t) {
                int krow = t * 32 + q31;
                int blk = (2 * s + hi) ^ (krow & 7);
                short8v kf = __builtin_bit_cast(short8v,
                    *(const ushort8v*)&Ks[cur][krow * 128 + blk * 8]);
                S[t] = __builtin_amdgcn_mfma_f32_32x32x16_bf16(kf, qf[s], S[t], 0, 0, 0);
            }
        }
        __builtin_amdgcn_s_setprio(0);

        if (kt >= 64) {  // causal mask within the new segment
            const int kb0 = (kt - 64) * 64 + 4 * hi;
            #pragma unroll
            for (int r = 0; r < 16; ++r) {
                int koff = kb0 + (r & 3) + 8 * (r >> 2);
                if (koff > qrow)      S[0][r] = -3.0e38f;
                if (koff + 32 > qrow) S[1][r] = -3.0e38f;
            }
        }

        float mx = fmaxf(S[0][0], S[1][0]);
        #pragma unroll
        for (int r = 1; r < 16; ++r) mx = fmaxf(mx, fmaxf(S[0][r], S[1][r]));
        mx = fmaxf(mx, __shfl_xor(mx, 32, 64));

        if (__ballot(mx > m_i + 8.f)) {
            float mnew = fmaxf(m_i, mx);
            float alpha = __expf(m_i - mnew);
            m_i = mnew;
            l_i *= alpha;
            #pragma unroll
            for (int r = 0; r < 16; ++r) {
                float ar = __shfl(alpha, (r & 3) + 8 * (r >> 2) + 4 * hi, 64);
                O[0][r] *= ar; O[1][r] *= ar; O[2][r] *= ar; O[3][r] *= ar;
            }
        }
        #pragma unroll
        for (int r = 0; r < 16; ++r) {
            S[0][r] = __expf(S[0][r] - m_i); l_i += S[0][r];
            S[1][r] = __expf(S[1][r] - m_i); l_i += S[1][r];
        }

        __builtin_amdgcn_s_setprio(1);
        #pragma unroll
        for (int j = 0; j < 4; ++j) {
            const int t = j >> 1, r0 = 8 * (j & 1);
            u32 a0, a1, b0, b1;
            asm("v_cvt_pk_bf16_f32 %0, %1, %2" : "=v"(a0) : "v"(S[t][r0+0]), "v"(S[t][r0+1]));
            asm("v_cvt_pk_bf16_f32 %0, %1, %2" : "=v"(a1) : "v"(S[t][r0+2]), "v"(S[t][r0+3]));
            asm("v_cvt_pk_bf16_f32 %0, %1, %2" : "=v"(b0) : "v"(S[t][r0+4]), "v"(S[t][r0+5]));
            asm("v_cvt_pk_bf16_f32 %0, %1, %2" : "=v"(b1) : "v"(S[t][r0+6]), "v"(S[t][r0+7]));
            asm("v_permlane32_swap_b32 %0, %1" : "+v"(a0), "+v"(b0));
            asm("v_permlane32_swap_b32 %0, %1" : "+v"(a1), "+v"(b1));
            u32x4v pw = {a0, a1, b0, b1};
            short8v pf = __builtin_bit_cast(short8v, pw);
            #pragma unroll
            for (int od = 0; od < 4; ++od) {
                int vrow = od * 32 + q31;
                int blk = (2 * j + hi) ^ (vrow & 7);
                short8v vf = __builtin_bit_cast(short8v,
                    *(const ushort8v*)&Vl[cur][vrow * 64 + blk * 8]);
                O[od] = __builtin_amdgcn_mfma_f32_32x32x16_bf16(pf, vf, O[od], 0, 0, 0);
            }
        }
        __builtin_amdgcn_s_setprio(0);

        __syncthreads();
        cur ^= 1;
    }

    // partial epilogue: unnormalized O (bf16) + (m, l)
    float lt = l_i + __shfl_xor(l_i, 32, 64);
    u16* Op = sp ? Op1 : Op0;
    const size_t pbase = ((size_t)bh * 4 + qt2) * 16384;
    #pragma unroll
    for (int r = 0; r < 16; ++r) {
        int qoff = (r & 3) + 8 * (r >> 2) + 4 * hi;
        size_t rowb = pbase + (size_t)(w * 32 + qoff) * 128 + q31;
        Op[rowb +  0] = f2bf(O[0][r]);
        Op[rowb + 32] = f2bf(O[1][r]);
        Op[rowb + 64] = f2bf(O[2][r]);
        Op[rowb + 96] = f2bf(O[3][r]);
    }
    if (hi == 0) {
        int qg = ((sp * 256 + bh * 4 + qt2) * 128 + w * 32 + q31);
        mlp[qg * 2 + 0] = m_i;
        mlp[qg * 2 + 1] = lt;
    }
}

// ---------------------------------------------------------------------------
// combine: merge the two key-split partials -> normalized y (bf16 head-split
// merged layout). Grid 256 = 64 bh x 4 q-tiles, 256 thr.
// ---------------------------------------------------------------------------
__global__ __launch_bounds__(256) void combine_kernel(
    const u16* __restrict__ Op0, const u16* __restrict__ Op1,
    const float* __restrict__ mlp, u16* __restrict__ yb) {
    const int p = blockIdx.x;
    const int bh = p >> 2, qt2 = p & 3;
    const int b = bh >> 4, h = bh & 15;
    const int q = threadIdx.x >> 1, dh = threadIdx.x & 1;
    const int base = (bh * 4 + qt2) * 128 + q;
    float m0 = mlp[base * 2], l0 = mlp[base * 2 + 1];
    float m1 = mlp[(256 * 128 + base) * 2], l1 = mlp[(256 * 128 + base) * 2 + 1];
    float M = fmaxf(m0, m1);
    float a0 = __expf(m0 - M), a1 = __expf(m1 - M);
    float invL = 1.0f / (l0 * a0 + l1 * a1);
    a0 *= invL; a1 *= invL;
    const size_t pb = ((size_t)bh * 4 + qt2) * 16384 + (size_t)q * 128 + dh * 64;
    u16* dst = yb + ((size_t)(b * 512 + qt2 * 128 + q)) * 2048 + h * 128 + dh * 64;
    #pragma unroll
    for (int j = 0; j < 8; ++j) {
        ushort8v o0 = *(const ushort8v*)(Op0 + pb + j * 8);
        ushort8v o1 = *(const ushort8v*)(Op1 + pb + j * 8);
        ushort8v o;
        #pragma unroll
        for (int e = 0; e < 8; ++e)
            o[e] = f2bf(bf2f(o0[e]) * a0 + bf2f(o1[e]) * a1);
        *(ushort8v*)(dst + j * 8) = o;
    }
}

// ---------------------------------------------------------------------------
extern "C" void kernel_launch(void* const* d_in, const int* in_sizes, int n_in,
                              void* d_out, int out_size, void* d_ws, size_t ws_size,
                              hipStream_t stream) {
    (void)in_sizes; (void)n_in; (void)out_size; (void)ws_size;
    const float* x   = (const float*)d_in[0];
    const int*   kq  = (const int*)d_in[1];
    const int*   vq  = (const int*)d_in[2];
    const float* ks  = (const float*)d_in[3];
    const float* vs  = (const float*)d_in[4];
    const float* Wq  = (const float*)d_in[5];
    const float* Wk  = (const float*)d_in[6];
    const float* Wv  = (const float*)d_in[7];
    const float* Wo  = (const float*)d_in[8];

    float* out  = (float*)d_out;
    float* y_o  = out;
    float* oktq = out + 4194304;
    float* ovtq = out + 37748736;
    float* oksc = out + 71303168;
    float* ovsc = out + 71565312;
    float* mlp  = out;   // y region is free until the final GEMM

    char* wsb = (char*)d_ws;
    u16* kcb = (u16*)(wsb);                       // 75.5 MB: [64][4608][128]
    u16* vtb = (u16*)(wsb + 75497472);            // 75.5 MB: [64][128][4608]
    u16* xb  = (u16*)(wsb + 150994944);           // 8 MB; later Opart split-0
    u16* qbf = (u16*)(wsb + 159383552);           // 8 MB
    u16* vnb = (u16*)(wsb + 167772160);           // 8 MB; later Opart split-1
    u16* ybf = (u16*)(wsb + 176160768);           // 8 MB
    u16* wb3 = (u16*)(wsb + 184549376);           // 24 MB: [Wq*s; Wk; Wv] bf16

    const float rscale = 0.08838834764831845f;    // 1/sqrt(128)
    const int n8 = 2048 * 2048 / 8;

    prep_cache_kernel<<<4096, 256, 0, stream>>>(kq, vq, ks, vs, kcb, vtb,
                                                oktq, ovtq, oksc, ovsc);
    convert_kernel<<<2048, 256, 0, stream>>>(x, xb, 1.0f, n8);
    convert_kernel<<<2048, 256, 0, stream>>>(Wq, wb3, rscale, n8);
    convert_kernel<<<2048, 256, 0, stream>>>(Wk, wb3 + 4194304, 1.0f, n8);
    convert_kernel<<<2048, 256, 0, stream>>>(Wv, wb3 + 8388608, 1.0f, n8);
    gemm_qkv_kernel<<<1536, 256, 0, stream>>>(xb, wb3, qbf, kcb, vnb);
    quant_new_kernel<<<512, 256, 0, stream>>>(kcb, vnb, vtb,
                                              oktq, ovtq, oksc, ovsc);
    attn_kernel<<<512, 256, 0, stream>>>(qbf, kcb, vtb, xb, vnb, mlp);
    combine_kernel<<<256, 256, 0, stream>>>(xb, vnb, mlp, ybf);
    convert_kernel<<<2048, 256, 0, stream>>>(Wo, wb3, 1.0f, n8);
    gemm_wo_kernel<<<512, 256, 0, stream>>>(ybf, wb3, y_o);
}

// Round 9
// 403.735 us; speedup vs baseline: 1.3942x; 1.0404x over previous
//
#include <hip/hip_runtime.h>
#include <hip/hip_fp16.h>

typedef float   f32x4   __attribute__((ext_vector_type(4)));
typedef float   f32x2   __attribute__((ext_vector_type(2)));
typedef float   f32x16  __attribute__((ext_vector_type(16)));
typedef short   short8v __attribute__((ext_vector_type(8)));
typedef unsigned short ushort8v __attribute__((ext_vector_type(8)));
typedef unsigned int   u32x4v __attribute__((ext_vector_type(4)));
typedef unsigned int   u32x2v __attribute__((ext_vector_type(2)));
typedef int     int2v   __attribute__((ext_vector_type(2)));
typedef int     int4v   __attribute__((ext_vector_type(4)));
typedef unsigned int   u32;
typedef unsigned short u16;

#define DEVI static __device__ __forceinline__

DEVI u16 f2bf(float f) {
    u32 u = __builtin_bit_cast(u32, f);
    u += 0x7FFFu + ((u >> 16) & 1u);   // RNE (inputs finite)
    return (u16)(u >> 16);
}
DEVI float bf2f(u16 h) { return __builtin_bit_cast(float, (u32)h << 16); }

// async global->LDS, 16B per lane; lds ptr must be wave-uniform (lane*16 added by HW)
DEVI void gl_lds16(const u16* g, u16* l) {
    __builtin_amdgcn_global_load_lds(
        (const __attribute__((address_space(1))) u32*)(const void*)g,
        (__attribute__((address_space(3))) u32*)(void*)l, 16, 0, 0);
}

// ---------------------------------------------------------------------------
// convert f32 -> bf16 (optionally scaled). n8 = elements/8.
// ---------------------------------------------------------------------------
__global__ __launch_bounds__(256) void convert_kernel(
    const float* __restrict__ src, u16* __restrict__ dst, float scale, int n8) {
    int idx = blockIdx.x * 256 + threadIdx.x;
    if (idx >= n8) return;
    const float* p = src + (size_t)idx * 8;
    f32x4 a = *(const f32x4*)p, b = *(const f32x4*)(p + 4);
    ushort8v o;
    o[0]=f2bf(a[0]*scale); o[1]=f2bf(a[1]*scale); o[2]=f2bf(a[2]*scale); o[3]=f2bf(a[3]*scale);
    o[4]=f2bf(b[0]*scale); o[5]=f2bf(b[1]*scale); o[6]=f2bf(b[2]*scale); o[7]=f2bf(b[3]*scale);
    *(ushort8v*)(dst + (size_t)idx * 8) = o;
}

// ---------------------------------------------------------------------------
// fused convert of 4 matrices: x->xb, Wq*rscale->wb3, Wk->wb3+4M, Wv->wb3+8M.
// Grid 8192 = 4 segs x 2048 blocks.
// ---------------------------------------------------------------------------
__global__ __launch_bounds__(256) void convert4_kernel(
    const float* __restrict__ x, const float* __restrict__ Wq,
    const float* __restrict__ Wk, const float* __restrict__ Wv,
    u16* __restrict__ xb, u16* __restrict__ wb3, float rscale) {
    const int seg = blockIdx.x >> 11;
    const int idx = (blockIdx.x & 2047) * 256 + threadIdx.x;
    const float* src; u16* dst; float scale = 1.0f;
    if (seg == 0)      { src = x;  dst = xb; }
    else if (seg == 1) { src = Wq; dst = wb3; scale = rscale; }
    else if (seg == 2) { src = Wk; dst = wb3 + 4194304; }
    else               { src = Wv; dst = wb3 + 8388608; }
    const float* p = src + (size_t)idx * 8;
    f32x4 a = *(const f32x4*)p, b = *(const f32x4*)(p + 4);
    ushort8v o;
    o[0]=f2bf(a[0]*scale); o[1]=f2bf(a[1]*scale); o[2]=f2bf(a[2]*scale); o[3]=f2bf(a[3]*scale);
    o[4]=f2bf(b[0]*scale); o[5]=f2bf(b[1]*scale); o[6]=f2bf(b[2]*scale); o[7]=f2bf(b[3]*scale);
    *(ushort8v*)(dst + (size_t)idx * 8) = o;
}

// ---------------------------------------------------------------------------
// prep_cache: dequant cache -> bf16 K rows (kcb rows 0..4095) + bf16 V^T cols
// 0..4095 + exact requant of window rows 512..4095. Grid 4096, 256 thr.
// 2 rows/wave, 4 elems/lane: 16B loads, 16B requant stores, 5-level reduce.
// ---------------------------------------------------------------------------
__global__ __launch_bounds__(256) void prep_cache_kernel(
    const int* __restrict__ kq, const int* __restrict__ vq,
    const float* __restrict__ ks, const float* __restrict__ vs,
    u16* __restrict__ kcb, u16* __restrict__ vt,
    float* __restrict__ oktq, float* __restrict__ ovtq,
    float* __restrict__ oksc, float* __restrict__ ovsc) {
    __shared__ u16 Vs[64][132];
    __shared__ float skL[64], svL[64];
    const int tid = threadIdx.x;
    const int bh = blockIdx.x >> 6, kt = blockIdx.x & 63;
    const int key0 = kt << 6;
    const size_t rowbase = (size_t)bh * 4096 + key0;
    if (tid < 64) { skL[tid] = ks[rowbase + tid]; svL[tid] = vs[rowbase + tid]; }
    __syncthreads();
    const int lane = tid & 63, w = tid >> 6;
    const int q31 = lane & 31, rh = lane >> 5;
    u32x2v* kcw = (u32x2v*)kcb;
    #pragma unroll 4
    for (int s = 0; s < 8; ++s) {
        const int key = s * 8 + w * 2 + rh;
        const size_t row = rowbase + key;
        const float sk = skL[key], sv = svL[key];
        int4v kv = *(const int4v*)(kq + row * 128 + q31 * 4);
        int4v vv = *(const int4v*)(vq + row * 128 + q31 * 4);
        f32x4 kx, vx;
        #pragma unroll
        for (int e = 0; e < 4; ++e) { kx[e] = (float)kv[e] * sk; vx[e] = (float)vv[e] * sv; }
        u32x2v kp, vp;
        kp[0] = (u32)f2bf(kx[0]) | ((u32)f2bf(kx[1]) << 16);
        kp[1] = (u32)f2bf(kx[2]) | ((u32)f2bf(kx[3]) << 16);
        vp[0] = (u32)f2bf(vx[0]) | ((u32)f2bf(vx[1]) << 16);
        vp[1] = (u32)f2bf(vx[2]) | ((u32)f2bf(vx[3]) << 16);
        kcw[(size_t)(bh * 4608 + key0 + key) * 32 + q31] = kp;
        *(u32x2v*)&Vs[key][q31 * 4] = vp;
        float kam = fmaxf(fmaxf(fabsf(kx[0]), fabsf(kx[1])), fmaxf(fabsf(kx[2]), fabsf(kx[3])));
        float vam = fmaxf(fmaxf(fabsf(vx[0]), fabsf(vx[1])), fmaxf(fabsf(vx[2]), fabsf(vx[3])));
        #pragma unroll
        for (int off = 1; off < 32; off <<= 1) {
            kam = fmaxf(kam, __shfl_xor(kam, off, 64));
            vam = fmaxf(vam, __shfl_xor(vam, off, 64));
        }
        const int r = key0 + key;
        if (r >= 512) {
            const size_t orow = (size_t)bh * 4096 + (size_t)(r - 512);
            float kscale = fmaxf(kam / 127.0f, 1e-8f);
            float vscale = fmaxf(vam / 127.0f, 1e-8f);
            float kinv = 1.0f / kscale, vinv = 1.0f / vscale;
            f32x4 ko, vo;
            #pragma unroll
            for (int e = 0; e < 4; ++e) {
                ko[e] = fminf(fmaxf(rintf(kx[e] * kinv), -127.f), 127.f);
                vo[e] = fminf(fmaxf(rintf(vx[e] * vinv), -127.f), 127.f);
            }
            *(f32x4*)(oktq + orow * 128 + q31 * 4) = ko;
            *(f32x4*)(ovtq + orow * 128 + q31 * 4) = vo;
            if (q31 == 0) {
                oksc[orow] = __half2float(__float2half(kscale));
                ovsc[orow] = __half2float(__float2half(vscale));
            }
        }
    }
    __syncthreads();
    const int d = tid >> 1, half = tid & 1;
    u16* obase = vt + ((size_t)bh * 128 + d) * 4608 + key0 + half * 32;
    #pragma unroll
    for (int c = 0; c < 4; ++c) {
        ushort8v tv;
        #pragma unroll
        for (int e = 0; e < 8; ++e) tv[e] = Vs[half * 32 + c * 8 + e][d];
        *(ushort8v*)(obase + c * 8) = tv;
    }
}

// ---------------------------------------------------------------------------
// fused QKV GEMM: C[m][n] = sum_k A[m][k]*W3[n][k], M=K=2048, N=6144.
// Grid 1536, 256 thr (4 waves 2x2 of 64x32), BM=128 BN=64 BK=64.
// ---------------------------------------------------------------------------
__global__ __launch_bounds__(256) void gemm_qkv_kernel(
    const u16* __restrict__ A, const u16* __restrict__ Bw,
    u16* __restrict__ qbf, u16* __restrict__ kcb, u16* __restrict__ vnb) {
    __shared__ u16 As[2][128 * 64];
    __shared__ u16 Bs[2][64 * 64];
    const int tid = threadIdx.x, lane = tid & 63, w = tid >> 6;
    const int sid = (blockIdx.x & 7) * 192 + (blockIdx.x >> 3);  // XCD-chunked
    const int bm = sid & 15, bn = sid >> 4;
    const int m0 = bm * 128, n0 = bn * 64;
    const int wm = (w >> 1) * 64, wn = (w & 1) * 32;
    const int r16 = lane & 15, kb = lane >> 4;

    f32x4 acc[4][2] = {};

    auto stage = [&](int bi, int k0) {
        #pragma unroll
        for (int i = 0; i < 4; ++i) {
            int s = i * 256 + tid;
            int row = s >> 3, l = (s & 7) ^ (row & 7);
            gl_lds16(A + (size_t)(m0 + row) * 2048 + k0 + l * 8,
                     &As[bi][(i * 256 + (tid & ~63)) * 8]);
        }
        #pragma unroll
        for (int i = 0; i < 2; ++i) {
            int s = i * 256 + tid;
            int row = s >> 3, l = (s & 7) ^ (row & 7);
            gl_lds16(Bw + (size_t)(n0 + row) * 2048 + k0 + l * 8,
                     &Bs[bi][(i * 256 + (tid & ~63)) * 8]);
        }
    };

    stage(0, 0);
    __syncthreads();
    int cur = 0;
    for (int t = 0; t < 32; ++t) {
        if (t < 31) stage(cur ^ 1, (t + 1) * 64);
        short8v af[4][2], bf[2][2];
        #pragma unroll
        for (int mf = 0; mf < 4; ++mf) {
            int row = wm + mf * 16 + r16;
            #pragma unroll
            for (int ksv = 0; ksv < 2; ++ksv) {
                int blk = (ksv * 4 + kb) ^ (row & 7);
                af[mf][ksv] = __builtin_bit_cast(short8v,
                    *(const ushort8v*)&As[cur][row * 64 + blk * 8]);
            }
        }
        #pragma unroll
        for (int nf = 0; nf < 2; ++nf) {
            int row = wn + nf * 16 + r16;
            #pragma unroll
            for (int ksv = 0; ksv < 2; ++ksv) {
                int blk = (ksv * 4 + kb) ^ (row & 7);
                bf[nf][ksv] = __builtin_bit_cast(short8v,
                    *(const ushort8v*)&Bs[cur][row * 64 + blk * 8]);
            }
        }
        #pragma unroll
        for (int mf = 0; mf < 4; ++mf)
            #pragma unroll
            for (int nf = 0; nf < 2; ++nf)
                #pragma unroll
                for (int ksv = 0; ksv < 2; ++ksv)
                    acc[mf][nf] = __builtin_amdgcn_mfma_f32_16x16x32_bf16(
                        af[mf][ksv], bf[nf][ksv], acc[mf][nf], 0, 0, 0);
        __syncthreads();
        cur ^= 1;
    }

    #pragma unroll
    for (int mf = 0; mf < 4; ++mf)
        #pragma unroll
        for (int nf = 0; nf < 2; ++nf)
            #pragma unroll
            for (int v = 0; v < 4; ++v) {
                int mg = m0 + wm + mf * 16 + kb * 4 + v;
                int ng = n0 + wn + nf * 16 + r16;
                int nb = ng >> 11, ngl = ng & 2047;
                u16 val = f2bf(acc[mf][nf][v]);
                if (nb == 1) {
                    size_t bh = (size_t)(mg >> 9) * 16 + (ngl >> 7);
                    kcb[(bh * 4608 + 4096 + (mg & 511)) * 128 + (ngl & 127)] = val;
                } else {
                    u16* dst = (nb == 0) ? qbf : vnb;
                    dst[(((size_t)(mg >> 9) * 16 + (ngl >> 7)) * 512 +
                         (mg & 511)) * 128 + (ngl & 127)] = val;
                }
            }
}

// ---------------------------------------------------------------------------
// W_o GEMM: C f32 row-major. (R5 known-good 4-wave version.)
// ---------------------------------------------------------------------------
__global__ __launch_bounds__(256) void gemm_wo_kernel(
    const u16* __restrict__ A, const u16* __restrict__ Bw,
    float* __restrict__ Cout) {
    __shared__ u16 As[2][128 * 64];
    __shared__ u16 Bs[2][64 * 64];
    const int tid = threadIdx.x, lane = tid & 63, w = tid >> 6;
    const int sid = (blockIdx.x & 7) * 64 + (blockIdx.x >> 3);
    const int bm = sid & 15, bn = sid >> 4;
    const int m0 = bm * 128, n0 = bn * 64;
    const int wm = (w >> 1) * 64, wn = (w & 1) * 32;
    const int r16 = lane & 15, kb = lane >> 4;

    f32x4 acc[4][2] = {};

    auto stage = [&](int bi, int k0) {
        #pragma unroll
        for (int i = 0; i < 4; ++i) {
            int s = i * 256 + tid;
            int row = s >> 3, l = (s & 7) ^ (row & 7);
            gl_lds16(A + (size_t)(m0 + row) * 2048 + k0 + l * 8,
                     &As[bi][(i * 256 + (tid & ~63)) * 8]);
        }
        #pragma unroll
        for (int i = 0; i < 2; ++i) {
            int s = i * 256 + tid;
            int row = s >> 3, l = (s & 7) ^ (row & 7);
            gl_lds16(Bw + (size_t)(n0 + row) * 2048 + k0 + l * 8,
                     &Bs[bi][(i * 256 + (tid & ~63)) * 8]);
        }
    };

    stage(0, 0);
    __syncthreads();
    int cur = 0;
    for (int t = 0; t < 32; ++t) {
        if (t < 31) stage(cur ^ 1, (t + 1) * 64);
        short8v af[4][2], bf[2][2];
        #pragma unroll
        for (int mf = 0; mf < 4; ++mf) {
            int row = wm + mf * 16 + r16;
            #pragma unroll
            for (int ksv = 0; ksv < 2; ++ksv) {
                int blk = (ksv * 4 + kb) ^ (row & 7);
                af[mf][ksv] = __builtin_bit_cast(short8v,
                    *(const ushort8v*)&As[cur][row * 64 + blk * 8]);
            }
        }
        #pragma unroll
        for (int nf = 0; nf < 2; ++nf) {
            int row = wn + nf * 16 + r16;
            #pragma unroll
            for (int ksv = 0; ksv < 2; ++ksv) {
                int blk = (ksv * 4 + kb) ^ (row & 7);
                bf[nf][ksv] = __builtin_bit_cast(short8v,
                    *(const ushort8v*)&Bs[cur][row * 64 + blk * 8]);
            }
        }
        #pragma unroll
        for (int mf = 0; mf < 4; ++mf)
            #pragma unroll
            for (int nf = 0; nf < 2; ++nf)
                #pragma unroll
                for (int ksv = 0; ksv < 2; ++ksv)
                    acc[mf][nf] = __builtin_amdgcn_mfma_f32_16x16x32_bf16(
                        af[mf][ksv], bf[nf][ksv], acc[mf][nf], 0, 0, 0);
        __syncthreads();
        cur ^= 1;
    }

    #pragma unroll
    for (int mf = 0; mf < 4; ++mf)
        #pragma unroll
        for (int nf = 0; nf < 2; ++nf)
            #pragma unroll
            for (int v = 0; v < 4; ++v) {
                int mg = m0 + wm + mf * 16 + kb * 4 + v;
                int ng = n0 + wn + nf * 16 + r16;
                Cout[(size_t)mg * 2048 + ng] = acc[mf][nf][v];
            }
}

// ---------------------------------------------------------------------------
// quant_new: quantize new K/V rows + V^T cols 4096..4607. Grid 512, 256 thr.
// 2 rows/wave, 4 elems/lane (8B loads, 16B stores, 5-level reduce).
// ---------------------------------------------------------------------------
__global__ __launch_bounds__(256) void quant_new_kernel(
    const u16* __restrict__ kcb, const u16* __restrict__ vnb,
    u16* __restrict__ vt,
    float* __restrict__ oktq, float* __restrict__ ovtq,
    float* __restrict__ oksc, float* __restrict__ ovsc) {
    __shared__ u16 Vs[64][132];
    const int tid = threadIdx.x;
    const int bh = blockIdx.x >> 3, kt = blockIdx.x & 7;
    const int i0 = kt << 6;
    const int lane = tid & 63, w = tid >> 6;
    const int q31 = lane & 31, rh = lane >> 5;
    #pragma unroll 4
    for (int s = 0; s < 8; ++s) {
        const int key = s * 8 + w * 2 + rh;
        const int i = i0 + key;
        u32x2v ku = *(const u32x2v*)(kcb + ((size_t)bh * 4608 + 4096 + i) * 128 + q31 * 4);
        u32x2v vu = *(const u32x2v*)(vnb + ((size_t)bh * 512 + i) * 128 + q31 * 4);
        f32x4 kx, vx;
        kx[0] = bf2f((u16)ku[0]); kx[1] = bf2f((u16)(ku[0] >> 16));
        kx[2] = bf2f((u16)ku[1]); kx[3] = bf2f((u16)(ku[1] >> 16));
        vx[0] = bf2f((u16)vu[0]); vx[1] = bf2f((u16)(vu[0] >> 16));
        vx[2] = bf2f((u16)vu[1]); vx[3] = bf2f((u16)(vu[1] >> 16));
        *(u32x2v*)&Vs[key][q31 * 4] = vu;
        float kam = fmaxf(fmaxf(fabsf(kx[0]), fabsf(kx[1])), fmaxf(fabsf(kx[2]), fabsf(kx[3])));
        float vam = fmaxf(fmaxf(fabsf(vx[0]), fabsf(vx[1])), fmaxf(fabsf(vx[2]), fabsf(vx[3])));
        #pragma unroll
        for (int off = 1; off < 32; off <<= 1) {
            kam = fmaxf(kam, __shfl_xor(kam, off, 64));
            vam = fmaxf(vam, __shfl_xor(vam, off, 64));
        }
        float kscale = fmaxf(kam / 127.0f, 1e-8f);
        float vscale = fmaxf(vam / 127.0f, 1e-8f);
        float kinv = 1.0f / kscale, vinv = 1.0f / vscale;
        const size_t orow = (size_t)bh * 4096 + 3584 + i;
        f32x4 ko, vo;
        #pragma unroll
        for (int e = 0; e < 4; ++e) {
            ko[e] = fminf(fmaxf(rintf(kx[e] * kinv), -127.f), 127.f);
            vo[e] = fminf(fmaxf(rintf(vx[e] * vinv), -127.f), 127.f);
        }
        *(f32x4*)(oktq + orow * 128 + q31 * 4) = ko;
        *(f32x4*)(ovtq + orow * 128 + q31 * 4) = vo;
        if (q31 == 0) {
            oksc[orow] = __half2float(__float2half(kscale));
            ovsc[orow] = __half2float(__float2half(vscale));
        }
    }
    __syncthreads();
    const int d = tid >> 1, half = tid & 1;
    u16* obase = vt + ((size_t)bh * 128 + d) * 4608 + 4096 + i0 + half * 32;
    #pragma unroll
    for (int c = 0; c < 4; ++c) {
        ushort8v tv;
        #pragma unroll
        for (int e = 0; e < 8; ++e) tv[e] = Vs[half * 32 + c * 8 + e][d];
        *(ushort8v*)(obase + c * 8) = tv;
    }
}

// ---------------------------------------------------------------------------
// attn split-K: 512 blocks = 64 bh x 4 q-tiles(128) x 2 key-splits.
// 4 waves x 32 q-rows; 32x32x16 MFMA; swapped QK^T; in-register softmax;
// cvt_pk+permlane P fragments; partial (m,l,O bf16) out. 8 waves/CU.
// ---------------------------------------------------------------------------
__global__ __launch_bounds__(256, 2) void attn_kernel(
    const u16* __restrict__ qb, const u16* __restrict__ kcb,
    const u16* __restrict__ vt, u16* __restrict__ Op0, u16* __restrict__ Op1,
    float* __restrict__ mlp) {
    __shared__ u16 Ks[2][64 * 128];
    __shared__ u16 Vl[2][128 * 64];

    const int tid = threadIdx.x, lane = tid & 63, w = tid >> 6;
    const int p = blockIdx.x;
    const int xcd = p & 7, i = p >> 3;
    const int qt2 = i & 3, sp = (i >> 2) & 1;
    const int bh = ((i >> 3) << 3) | xcd;      // bh%8 == xcd
    const int q31 = lane & 31, hi = lane >> 5;
    const int qrow = qt2 * 128 + w * 32 + q31;

    const u16* qp = qb + ((size_t)bh * 512 + qrow) * 128 + hi * 8;
    short8v qf[8];
    #pragma unroll
    for (int s = 0; s < 8; ++s)
        qf[s] = __builtin_bit_cast(short8v, *(const ushort8v*)(qp + s * 16));

    f32x16 O[4] = {};
    float m_i = -3.0e38f, l_i = 0.f;

    const size_t kbase = (size_t)bh * 4608 * 128;
    const size_t vbase = (size_t)bh * 128 * 4608;
    const int ktA = sp ? 32 : 0;
    const int ktB = sp ? (66 + 2 * qt2) : 32;

    auto STAGE = [&](int bi, int kt) {
        #pragma unroll
        for (int ii = 0; ii < 4; ++ii) {
            int s = ii * 256 + tid;
            int row = s >> 4, l = (s & 15) ^ (row & 7);
            gl_lds16(kcb + kbase + (size_t)(kt * 64 + row) * 128 + l * 8,
                     &Ks[bi][(ii * 256 + (tid & ~63)) * 8]);
        }
        #pragma unroll
        for (int ii = 0; ii < 4; ++ii) {
            int s = ii * 256 + tid;
            int row = s >> 3, l = (s & 7) ^ (row & 7);
            gl_lds16(vt + vbase + (size_t)row * 4608 + kt * 64 + l * 8,
                     &Vl[bi][(ii * 256 + (tid & ~63)) * 8]);
        }
    };

    STAGE(0, ktA);
    __syncthreads();
    int cur = 0;
    for (int kt = ktA; kt < ktB; ++kt) {
        if (kt + 1 < ktB) STAGE(cur ^ 1, kt + 1);

        f32x16 S[2] = {};
        __builtin_amdgcn_s_setprio(1);
        #pragma unroll
        for (int s = 0; s < 8; ++s) {
            #pragma unroll
            for (int t = 0; t < 2; ++t) {
                int krow = t * 32 + q31;
                int blk = (2 * s + hi) ^ (krow & 7);
                short8v kf = __builtin_bit_cast(short8v,
                    *(const ushort8v*)&Ks[cur][krow * 128 + blk * 8]);
                S[t] = __builtin_amdgcn_mfma_f32_32x32x16_bf16(kf, qf[s], S[t], 0, 0, 0);
            }
        }
        __builtin_amdgcn_s_setprio(0);

        if (kt >= 64) {  // causal mask within the new segment
            const int kb0 = (kt - 64) * 64 + 4 * hi;
            #pragma unroll
            for (int r = 0; r < 16; ++r) {
                int koff = kb0 + (r & 3) + 8 * (r >> 2);
                if (koff > qrow)      S[0][r] = -3.0e38f;
                if (koff + 32 > qrow) S[1][r] = -3.0e38f;
            }
        }

        float mx = fmaxf(S[0][0], S[1][0]);
        #pragma unroll
        for (int r = 1; r < 16; ++r) mx = fmaxf(mx, fmaxf(S[0][r], S[1][r]));
        mx = fmaxf(mx, __shfl_xor(mx, 32, 64));

        if (__ballot(mx > m_i + 8.f)) {
            float mnew = fmaxf(m_i, mx);
            float alpha = __expf(m_i - mnew);
            m_i = mnew;
            l_i *= alpha;
            #pragma unroll
            for (int r = 0; r < 16; ++r) {
                float ar = __shfl(alpha, (r & 3) + 8 * (r >> 2) + 4 * hi, 64);
                O[0][r] *= ar; O[1][r] *= ar; O[2][r] *= ar; O[3][r] *= ar;
            }
        }
        #pragma unroll
        for (int r = 0; r < 16; ++r) {
            S[0][r] = __expf(S[0][r] - m_i); l_i += S[0][r];
            S[1][r] = __expf(S[1][r] - m_i); l_i += S[1][r];
        }

        __builtin_amdgcn_s_setprio(1);
        #pragma unroll
        for (int j = 0; j < 4; ++j) {
            const int t = j >> 1, r0 = 8 * (j & 1);
            u32 a0, a1, b0, b1;
            asm("v_cvt_pk_bf16_f32 %0, %1, %2" : "=v"(a0) : "v"(S[t][r0+0]), "v"(S[t][r0+1]));
            asm("v_cvt_pk_bf16_f32 %0, %1, %2" : "=v"(a1) : "v"(S[t][r0+2]), "v"(S[t][r0+3]));
            asm("v_cvt_pk_bf16_f32 %0, %1, %2" : "=v"(b0) : "v"(S[t][r0+4]), "v"(S[t][r0+5]));
            asm("v_cvt_pk_bf16_f32 %0, %1, %2" : "=v"(b1) : "v"(S[t][r0+6]), "v"(S[t][r0+7]));
            asm("v_permlane32_swap_b32 %0, %1" : "+v"(a0), "+v"(b0));
            asm("v_permlane32_swap_b32 %0, %1" : "+v"(a1), "+v"(b1));
            u32x4v pw = {a0, a1, b0, b1};
            short8v pf = __builtin_bit_cast(short8v, pw);
            #pragma unroll
            for (int od = 0; od < 4; ++od) {
                int vrow = od * 32 + q31;
                int blk = (2 * j + hi) ^ (vrow & 7);
                short8v vf = __builtin_bit_cast(short8v,
                    *(const ushort8v*)&Vl[cur][vrow * 64 + blk * 8]);
                O[od] = __builtin_amdgcn_mfma_f32_32x32x16_bf16(pf, vf, O[od], 0, 0, 0);
            }
        }
        __builtin_amdgcn_s_setprio(0);

        __syncthreads();
        cur ^= 1;
    }

    // partial epilogue: unnormalized O (bf16) + (m, l)
    float lt = l_i + __shfl_xor(l_i, 32, 64);
    u16* Op = sp ? Op1 : Op0;
    const size_t pbase = ((size_t)bh * 4 + qt2) * 16384;
    #pragma unroll
    for (int r = 0; r < 16; ++r) {
        int qoff = (r & 3) + 8 * (r >> 2) + 4 * hi;
        size_t rowb = pbase + (size_t)(w * 32 + qoff) * 128 + q31;
        Op[rowb +  0] = f2bf(O[0][r]);
        Op[rowb + 32] = f2bf(O[1][r]);
        Op[rowb + 64] = f2bf(O[2][r]);
        Op[rowb + 96] = f2bf(O[3][r]);
    }
    if (hi == 0) {
        int qg = ((sp * 256 + bh * 4 + qt2) * 128 + w * 32 + q31);
        mlp[qg * 2 + 0] = m_i;
        mlp[qg * 2 + 1] = lt;
    }
}

// ---------------------------------------------------------------------------
// combine: merge the two key-split partials -> normalized y (bf16 head-split
// merged layout). Grid 256 = 64 bh x 4 q-tiles, 256 thr.
// ---------------------------------------------------------------------------
__global__ __launch_bounds__(256) void combine_kernel(
    const u16* __restrict__ Op0, const u16* __restrict__ Op1,
    const float* __restrict__ mlp, u16* __restrict__ yb) {
    const int p = blockIdx.x;
    const int bh = p >> 2, qt2 = p & 3;
    const int b = bh >> 4, h = bh & 15;
    const int q = threadIdx.x >> 1, dh = threadIdx.x & 1;
    const int base = (bh * 4 + qt2) * 128 + q;
    float m0 = mlp[base * 2], l0 = mlp[base * 2 + 1];
    float m1 = mlp[(256 * 128 + base) * 2], l1 = mlp[(256 * 128 + base) * 2 + 1];
    float M = fmaxf(m0, m1);
    float a0 = __expf(m0 - M), a1 = __expf(m1 - M);
    float invL = 1.0f / (l0 * a0 + l1 * a1);
    a0 *= invL; a1 *= invL;
    const size_t pb = ((size_t)bh * 4 + qt2) * 16384 + (size_t)q * 128 + dh * 64;
    u16* dst = yb + ((size_t)(b * 512 + qt2 * 128 + q)) * 2048 + h * 128 + dh * 64;
    #pragma unroll
    for (int j = 0; j < 8; ++j) {
        ushort8v o0 = *(const ushort8v*)(Op0 + pb + j * 8);
        ushort8v o1 = *(const ushort8v*)(Op1 + pb + j * 8);
        ushort8v o;
        #pragma unroll
        for (int e = 0; e < 8; ++e)
            o[e] = f2bf(bf2f(o0[e]) * a0 + bf2f(o1[e]) * a1);
        *(ushort8v*)(dst + j * 8) = o;
    }
}

// ---------------------------------------------------------------------------
extern "C" void kernel_launch(void* const* d_in, const int* in_sizes, int n_in,
                              void* d_out, int out_size, void* d_ws, size_t ws_size,
                              hipStream_t stream) {
    (void)in_sizes; (void)n_in; (void)out_size; (void)ws_size;
    const float* x   = (const float*)d_in[0];
    const int*   kq  = (const int*)d_in[1];
    const int*   vq  = (const int*)d_in[2];
    const float* ks  = (const float*)d_in[3];
    const float* vs  = (const float*)d_in[4];
    const float* Wq  = (const float*)d_in[5];
    const float* Wk  = (const float*)d_in[6];
    const float* Wv  = (const float*)d_in[7];
    const float* Wo  = (const float*)d_in[8];

    float* out  = (float*)d_out;
    float* y_o  = out;
    float* oktq = out + 4194304;
    float* ovtq = out + 37748736;
    float* oksc = out + 71303168;
    float* ovsc = out + 71565312;
    float* mlp  = out;   // y region is free until the final GEMM

    char* wsb = (char*)d_ws;
    u16* kcb = (u16*)(wsb);                       // 75.5 MB: [64][4608][128]
    u16* vtb = (u16*)(wsb + 75497472);            // 75.5 MB: [64][128][4608]
    u16* xb  = (u16*)(wsb + 150994944);           // 8 MB; later Opart split-0
    u16* qbf = (u16*)(wsb + 159383552);           // 8 MB
    u16* vnb = (u16*)(wsb + 167772160);           // 8 MB; later Opart split-1
    u16* ybf = (u16*)(wsb + 176160768);           // 8 MB
    u16* wb3 = (u16*)(wsb + 184549376);           // 24 MB: [Wq*s; Wk; Wv] bf16

    const float rscale = 0.08838834764831845f;    // 1/sqrt(128)
    const int n8 = 2048 * 2048 / 8;

    prep_cache_kernel<<<4096, 256, 0, stream>>>(kq, vq, ks, vs, kcb, vtb,
                                                oktq, ovtq, oksc, ovsc);
    convert4_kernel<<<8192, 256, 0, stream>>>(x, Wq, Wk, Wv, xb, wb3, rscale);
    gemm_qkv_kernel<<<1536, 256, 0, stream>>>(xb, wb3, qbf, kcb, vnb);
    quant_new_kernel<<<512, 256, 0, stream>>>(kcb, vnb, vtb,
                                              oktq, ovtq, oksc, ovsc);
    attn_kernel<<<512, 256, 0, stream>>>(qbf, kcb, vtb, xb, vnb, mlp);
    combine_kernel<<<256, 256, 0, stream>>>(xb, vnb, mlp, ybf);
    convert_kernel<<<2048, 256, 0, stream>>>(Wo, wb3, 1.0f, n8);
    gemm_wo_kernel<<<512, 256, 0, stream>>>(ybf, wb3, y_o);
}